// Round 1
// baseline (11505.718 us; speedup 1.0000x reference)
//
#include <hip/hip_runtime.h>
#include <hip/hip_bf16.h>
#include <cstdint>

// Problem constants
#define BB   64
#define TT   128
#define KK   4
#define LL   128
#define SS   64
#define AA   64
#define DQN  32
#define UU   256
#define NAOUT 164
#define WDIM 300
#define PDIM 64
#define ADIM 64

typedef unsigned short ushort_t;
typedef unsigned int   uint_t;

__device__ __forceinline__ float bf2f(ushort_t s) {
    return __uint_as_float(((uint_t)s) << 16);
}
__device__ __forceinline__ ushort_t f2bf(float x) {
    __hip_bfloat16 h = __float2bfloat16(x);
    return *reinterpret_cast<ushort_t*>(&h);
}
__device__ __forceinline__ float sigm(float x) { return 1.0f / (1.0f + expf(-x)); }

// bf16 pair unpack: lo = low 16 bits as bf16, hi = high 16 bits as bf16.
__device__ __forceinline__ float blo(uint_t w) { return __uint_as_float(w << 16); }
__device__ __forceinline__ float bhi(uint_t w) { return __uint_as_float(w & 0xFFFF0000u); }

// Dual-dtype load: F32=true -> buffer holds float32; false -> bf16.
template<bool F32>
__device__ __forceinline__ float ld1(const void* p_, size_t i) {
    if constexpr (F32) return reinterpret_cast<const float*>(p_)[i];
    else               return bf2f(reinterpret_cast<const ushort_t*>(p_)[i]);
}

struct P {
    // int inputs
    const int *tree_word_id, *tree_pos_id, *token_word_id, *token_pos_id, *history_action_id,
              *buff_top_id, *deque_word_id, *deque_pos_id, *deque_length, *children_order,
              *stack_order, *stack_length, *token_length, *history_action_length;
    // float-family params (dtype resolved at runtime)
    const void *word_emb, *pos_emb, *act_emb, *wd_W, *wd_b, *tree_W, *tree_b,
        *stack0_W, *stack0_b, *stack1_W, *stack1_b, *fw0_W, *fw0_b, *bw0_W, *bw0_b,
        *fw1_W, *fw1_b, *bw1_W, *bw1_b, *act0_W, *act0_b, *act1_W, *act1_b,
        *dq0_W, *dq0_b, *dq1_W, *dq1_b, *fin_W, *fin_b;
    // workspace
    int* flag;                          // [0]: 0 = bf16 world, 1 = f32 world
    float *stack_h, *fw1_h, *fw_top, *bw_top, *bw_bottom, *act_h, *dq_h;  // f32
    float *tree_e;                      // f32! (tree dynamics are chaotic — no bf16 seed)
    ushort_t *token_e, *deque_e, *x1;   // bf16 (contractive chains tolerate rounding)
    float *H, *C;                       // f32
    // packed bf16 weights: pk[r2][u][g*2+rp] = W[2*r2+rp][256*g+u]
    // thread u loads one dwordx4 per 2 rows -> 8x fewer load instrs vs scalar ushort.
    ushort_t *pk_tree, *pk_stack0, *pk_stack1, *pk_fw0, *pk_bw0, *pk_fw1, *pk_bw1,
             *pk_act0, *pk_act1, *pk_dq0, *pk_dq1;
};

// ---------------------------------------------------------------------------
// dtype detector (validated: bf16 world detected in rounds 3/4)
// ---------------------------------------------------------------------------
__global__ void detect_kernel(const uint_t* w, int* flag) {
    __shared__ int cnt;
    if (threadIdx.x == 0) cnt = 0;
    __syncthreads();
    int local = 0;
    for (int i = threadIdx.x; i < 256; i += 64) {
        uint_t lo = w[i] & 0xFFFFu;
        uint_t e  = (lo >> 7) & 0xFFu;
        if (lo == 0u || (e >= 0x6Cu && e <= 0x7Fu)) local++;
    }
    atomicAdd(&cnt, local);
    __syncthreads();
    if (threadIdx.x == 0) flag[0] = (cnt >= 200) ? 0 : 1;
}

__global__ void sentinel_kernel(void* out, float v) {
    if (threadIdx.x == 0) {
        reinterpret_cast<float*>(out)[0] = v;
        reinterpret_cast<__hip_bfloat16*>(out)[2] = __float2bfloat16(v);
    }
}

// ---------------------------------------------------------------------------
// Weight packing (bf16 world only). One block per r2 (pair of rows).
// ---------------------------------------------------------------------------
__global__ __launch_bounds__(256) void pack_kernel(P p) {
    if (p.flag[0] != 0) return;   // f32 world uses the unpacked fallback path
    const int blk = blockIdx.x;
    const ushort_t* src; ushort_t* dst; int r2;
    if      (blk < 256)  { src = (const ushort_t*)p.tree_W;   dst = p.pk_tree;   r2 = blk;        }
    else if (blk < 512)  { src = (const ushort_t*)p.stack0_W; dst = p.pk_stack0; r2 = blk - 256;  }
    else if (blk < 768)  { src = (const ushort_t*)p.stack1_W; dst = p.pk_stack1; r2 = blk - 512;  }
    else if (blk < 1024) { src = (const ushort_t*)p.fw0_W;    dst = p.pk_fw0;    r2 = blk - 768;  }
    else if (blk < 1280) { src = (const ushort_t*)p.bw0_W;    dst = p.pk_bw0;    r2 = blk - 1024; }
    else if (blk < 1664) { src = (const ushort_t*)p.fw1_W;    dst = p.pk_fw1;    r2 = blk - 1280; }
    else if (blk < 2048) { src = (const ushort_t*)p.bw1_W;    dst = p.pk_bw1;    r2 = blk - 1664; }
    else if (blk < 2208) { src = (const ushort_t*)p.act0_W;   dst = p.pk_act0;   r2 = blk - 2048; }
    else if (blk < 2464) { src = (const ushort_t*)p.act1_W;   dst = p.pk_act1;   r2 = blk - 2208; }
    else if (blk < 2720) { src = (const ushort_t*)p.dq0_W;    dst = p.pk_dq0;    r2 = blk - 2464; }
    else                 { src = (const ushort_t*)p.dq1_W;    dst = p.pk_dq1;    r2 = blk - 2720; }

    const int u = threadIdx.x;
    const ushort_t* s0 = src + (size_t)(2 * r2) * 1024;
    const uint_t a0 = s0[u],        a1 = s0[256 + u],  a2 = s0[512 + u],  a3 = s0[768 + u];
    const uint_t b0 = s0[1024 + u], b1 = s0[1280 + u], b2 = s0[1536 + u], b3 = s0[1792 + u];
    uint4 v;
    v.x = a0 | (b0 << 16);   // gate0: row 2r2 (lo) | row 2r2+1 (hi)
    v.y = a1 | (b1 << 16);
    v.z = a2 | (b2 << 16);
    v.w = a3 | (b3 << 16);
    reinterpret_cast<uint4*>(dst)[(size_t)r2 * 256 + u] = v;
}

// ---------------------------------------------------------------------------
// Embedding (one row per block): e = relu(concat(word_emb[wid], pos_emb[pid]) @ wd_W + wd_b)
// Tree rows -> f32 output; token/deque rows -> bf16 output.
// ---------------------------------------------------------------------------
template<bool F32>
__device__ void embed_impl(const P& p, float* s_e) {
    const int u   = threadIdx.x;
    const int row = blockIdx.x;

    const int* wid; const int* pid; int rowbase; int which;
    float* out_f = nullptr; ushort_t* out_b = nullptr;
    if (row < BB * TT) {
        wid = p.tree_word_id; pid = p.tree_pos_id; rowbase = row; which = 0;
        out_f = p.tree_e;
    } else if (row < BB * TT + BB * LL) {
        wid = p.token_word_id; pid = p.token_pos_id; rowbase = row - BB * TT; which = 1;
        out_b = p.token_e;
    } else {
        wid = p.deque_word_id; pid = p.deque_pos_id; rowbase = row - BB * TT - BB * LL; which = 2;
        out_b = p.deque_e;
    }

    const int w  = wid[rowbase];
    const int pp = pid[rowbase];
    for (int e = u; e < WDIM + PDIM; e += 256) {
        s_e[e] = (e < WDIM) ? ld1<F32>(p.word_emb, (size_t)w * WDIM + e)
                            : ld1<F32>(p.pos_emb, (size_t)pp * PDIM + (e - WDIM));
    }
    __syncthreads();

    float acc = ld1<F32>(p.wd_b, u);
    for (int r = 0; r < WDIM + PDIM; ++r)
        acc = fmaf(s_e[r], ld1<F32>(p.wd_W, (size_t)r * UU + u), acc);
    acc = fmaxf(acc, 0.f);
    if (which == 0) out_f[(size_t)rowbase * UU + u] = acc;
    else            out_b[(size_t)rowbase * UU + u] = f2bf(acc);
}

__global__ __launch_bounds__(256) void embed_kernel(P p) {
    __shared__ __align__(16) float s_e[384];
    if (p.flag[0] == 1) embed_impl<true>(p, s_e);
    else                embed_impl<false>(p, s_e);
}

// ---------------------------------------------------------------------------
// One LSTM step (f32 fallback path, unpacked weights). Thread u owns unit u
// (gate cols u, 256+u, 512+u, 768+u). s_xh = [x (INT-256) | h (256)].
// ---------------------------------------------------------------------------
template<int INT, bool F32>
__device__ __forceinline__ float lstm_step(const void* __restrict__ W,
                                           const void* __restrict__ bias,
                                           const float* __restrict__ s_xh,
                                           float& c) {
    const int u = threadIdx.x;
    float zi = 0.f, zj = 0.f, zf = 0.f, zo = 0.f;
    for (int r = 0; r < INT; ++r) {
        const float xv = s_xh[r];
        const size_t ro = (size_t)r * 1024;
        zi = fmaf(xv, ld1<F32>(W, ro + u),       zi);
        zj = fmaf(xv, ld1<F32>(W, ro + 256 + u), zj);
        zf = fmaf(xv, ld1<F32>(W, ro + 512 + u), zf);
        zo = fmaf(xv, ld1<F32>(W, ro + 768 + u), zo);
    }
    zi += ld1<F32>(bias, u);
    zj += ld1<F32>(bias, 256 + u);
    zf += ld1<F32>(bias, 512 + u);
    zo += ld1<F32>(bias, 768 + u);
    const float nc = c * sigm(zf + 1.0f) + sigm(zi) * tanhf(zj);
    c = nc;
    return tanhf(nc) * sigm(zo);
}

// ---------------------------------------------------------------------------
// One LSTM step, packed-bf16 weights: one dwordx4 load per 2 rows.
// ---------------------------------------------------------------------------
template<int R>
__device__ __forceinline__ float lstm_step_pk(const ushort_t* __restrict__ Wp,
                                              const void* __restrict__ bias,
                                              const float* __restrict__ s_xh,
                                              float& c) {
    const int u = threadIdx.x;
    const uint4* __restrict__ W4 = reinterpret_cast<const uint4*>(Wp) + u;
    float zi = ld1<false>(bias, u);
    float zj = ld1<false>(bias, 256 + u);
    float zf = ld1<false>(bias, 512 + u);
    float zo = ld1<false>(bias, 768 + u);
    #pragma unroll 16
    for (int r2 = 0; r2 < R / 2; ++r2) {
        const uint4  w  = W4[(size_t)r2 * 256];
        const float2 xv = *reinterpret_cast<const float2*>(s_xh + 2 * r2);
        zi = fmaf(xv.x, blo(w.x), zi); zi = fmaf(xv.y, bhi(w.x), zi);
        zj = fmaf(xv.x, blo(w.y), zj); zj = fmaf(xv.y, bhi(w.y), zj);
        zf = fmaf(xv.x, blo(w.z), zf); zf = fmaf(xv.y, bhi(w.z), zf);
        zo = fmaf(xv.x, blo(w.w), zo); zo = fmaf(xv.y, bhi(w.w), zo);
    }
    const float nc = c * sigm(zf + 1.0f) + sigm(zi) * tanhf(zj);
    c = nc;
    return tanhf(nc) * sigm(zo);
}

// ---------------------------------------------------------------------------
// Phase 1 — tree (f32 fallback)
// ---------------------------------------------------------------------------
template<bool F32>
__device__ void run_tree(int b, const P& p, float* smem) {
    const int u = threadIdx.x;
    float* s_x  = smem;          // 256
    float* s_hj = smem + 256;    // 256
    float* s_hk = smem + 512;    // 1024
    float* H = p.H;
    float* C = p.C;
    H[(size_t)b * UU + u] = 0.f;
    C[(size_t)b * UU + u] = 0.f;

    const void* W    = p.tree_W;  // (512,1024): cols i|j|o|f
    const void* bias = p.tree_b;

    for (int i = 0; i < TT; ++i) {
        const int* co = p.children_order + ((size_t)b * TT + i) * KK;
        const int i0 = co[0], i1 = co[1], i2 = co[2], i3 = co[3];
        const float h0 = H[((size_t)i0 * BB + b) * UU + u];
        const float h1 = H[((size_t)i1 * BB + b) * UU + u];
        const float h2 = H[((size_t)i2 * BB + b) * UU + u];
        const float h3 = H[((size_t)i3 * BB + b) * UU + u];
        const float c0 = C[((size_t)i0 * BB + b) * UU + u];
        const float c1 = C[((size_t)i1 * BB + b) * UU + u];
        const float c2 = C[((size_t)i2 * BB + b) * UU + u];
        const float c3 = C[((size_t)i3 * BB + b) * UU + u];
        s_x[u]        = p.tree_e[((size_t)b * TT + i) * UU + u];
        s_hk[u]       = h0;
        s_hk[256 + u] = h1;
        s_hk[512 + u] = h2;
        s_hk[768 + u] = h3;
        s_hj[u]       = h0 + h1 + h2 + h3;
        __syncthreads();

        float zi = 0.f, zj = 0.f, zo = 0.f, fx = 0.f;
        float f0 = 0.f, f1 = 0.f, f2 = 0.f, f3 = 0.f;
        for (int r = 0; r < 256; ++r) {           // x rows [0,256)
            const float xv = s_x[r];
            const size_t ro = (size_t)r * 1024;
            zi = fmaf(xv, ld1<F32>(W, ro + u),       zi);
            zj = fmaf(xv, ld1<F32>(W, ro + 256 + u), zj);
            zo = fmaf(xv, ld1<F32>(W, ro + 512 + u), zo);
            fx = fmaf(xv, ld1<F32>(W, ro + 768 + u), fx);
        }
        for (int r = 0; r < 256; ++r) {           // h rows [256,512)
            const size_t ro = (size_t)(256 + r) * 1024;
            const float hjv = s_hj[r];
            zi = fmaf(hjv, ld1<F32>(W, ro + u),       zi);
            zj = fmaf(hjv, ld1<F32>(W, ro + 256 + u), zj);
            zo = fmaf(hjv, ld1<F32>(W, ro + 512 + u), zo);
            const float wf = ld1<F32>(W, ro + 768 + u);
            f0 = fmaf(s_hk[r],       wf, f0);
            f1 = fmaf(s_hk[256 + r], wf, f1);
            f2 = fmaf(s_hk[512 + r], wf, f2);
            f3 = fmaf(s_hk[768 + r], wf, f3);
        }
        zi += ld1<F32>(bias, u);
        zj += ld1<F32>(bias, 256 + u);
        zo += ld1<F32>(bias, 512 + u);
        fx += ld1<F32>(bias, 768 + u) + 1.0f;

        const float fsum = c0 * sigm(fx + f0) + c1 * sigm(fx + f1)
                         + c2 * sigm(fx + f2) + c3 * sigm(fx + f3);
        const float nc = fsum + sigm(zi) * tanhf(zj);
        const float nh = tanhf(nc) * sigm(zo);
        __syncthreads();
        H[((size_t)(i + 1) * BB + b) * UU + u] = nh;
        C[((size_t)(i + 1) * BB + b) * UU + u] = nc;
    }
}

// Phase 1 — tree (packed-bf16 fast path)
__device__ void run_tree_pk(int b, const P& p, float* smem) {
    const int u = threadIdx.x;
    float* s_x  = smem;          // 256
    float* s_hj = smem + 256;    // 256
    float* s_hk = smem + 512;    // 1024
    float* H = p.H;
    float* C = p.C;
    H[(size_t)b * UU + u] = 0.f;
    C[(size_t)b * UU + u] = 0.f;

    const uint4* __restrict__ W4 = reinterpret_cast<const uint4*>(p.pk_tree) + u;
    const void* bias = p.tree_b;
    const float bi = ld1<false>(bias, u);
    const float bj = ld1<false>(bias, 256 + u);
    const float bo = ld1<false>(bias, 512 + u);
    const float bf = ld1<false>(bias, 768 + u) + 1.0f;

    for (int i = 0; i < TT; ++i) {
        const int* co = p.children_order + ((size_t)b * TT + i) * KK;
        const int i0 = co[0], i1 = co[1], i2 = co[2], i3 = co[3];
        const float h0 = H[((size_t)i0 * BB + b) * UU + u];
        const float h1 = H[((size_t)i1 * BB + b) * UU + u];
        const float h2 = H[((size_t)i2 * BB + b) * UU + u];
        const float h3 = H[((size_t)i3 * BB + b) * UU + u];
        const float c0 = C[((size_t)i0 * BB + b) * UU + u];
        const float c1 = C[((size_t)i1 * BB + b) * UU + u];
        const float c2 = C[((size_t)i2 * BB + b) * UU + u];
        const float c3 = C[((size_t)i3 * BB + b) * UU + u];
        s_x[u]        = p.tree_e[((size_t)b * TT + i) * UU + u];
        s_hk[u]       = h0;
        s_hk[256 + u] = h1;
        s_hk[512 + u] = h2;
        s_hk[768 + u] = h3;
        s_hj[u]       = h0 + h1 + h2 + h3;
        __syncthreads();

        float zi = bi, zj = bj, zo = bo, fx = bf;
        #pragma unroll 8
        for (int r2 = 0; r2 < 128; ++r2) {        // x rows [0,256), paired
            const uint4  w  = W4[(size_t)r2 * 256];
            const float2 xv = *reinterpret_cast<const float2*>(s_x + 2 * r2);
            zi = fmaf(xv.x, blo(w.x), zi); zi = fmaf(xv.y, bhi(w.x), zi);
            zj = fmaf(xv.x, blo(w.y), zj); zj = fmaf(xv.y, bhi(w.y), zj);
            zo = fmaf(xv.x, blo(w.z), zo); zo = fmaf(xv.y, bhi(w.z), zo);
            fx = fmaf(xv.x, blo(w.w), fx); fx = fmaf(xv.y, bhi(w.w), fx);
        }
        float f0 = 0.f, f1 = 0.f, f2 = 0.f, f3 = 0.f;
        #pragma unroll 8
        for (int r2 = 128; r2 < 256; ++r2) {      // h rows [256,512), paired
            const uint4 w = W4[(size_t)r2 * 256];
            const int r = 2 * (r2 - 128);
            const float2 hj = *reinterpret_cast<const float2*>(s_hj + r);
            zi = fmaf(hj.x, blo(w.x), zi); zi = fmaf(hj.y, bhi(w.x), zi);
            zj = fmaf(hj.x, blo(w.y), zj); zj = fmaf(hj.y, bhi(w.y), zj);
            zo = fmaf(hj.x, blo(w.z), zo); zo = fmaf(hj.y, bhi(w.z), zo);
            const float wf0 = blo(w.w), wf1 = bhi(w.w);
            float2 k;
            k = *reinterpret_cast<const float2*>(s_hk + r);       f0 = fmaf(k.x, wf0, f0); f0 = fmaf(k.y, wf1, f0);
            k = *reinterpret_cast<const float2*>(s_hk + 256 + r); f1 = fmaf(k.x, wf0, f1); f1 = fmaf(k.y, wf1, f1);
            k = *reinterpret_cast<const float2*>(s_hk + 512 + r); f2 = fmaf(k.x, wf0, f2); f2 = fmaf(k.y, wf1, f2);
            k = *reinterpret_cast<const float2*>(s_hk + 768 + r); f3 = fmaf(k.x, wf0, f3); f3 = fmaf(k.y, wf1, f3);
        }
        const float fsum = c0 * sigm(fx + f0) + c1 * sigm(fx + f1)
                         + c2 * sigm(fx + f2) + c3 * sigm(fx + f3);
        const float nc = fsum + sigm(zi) * tanhf(zj);
        const float nh = tanhf(nc) * sigm(zo);
        __syncthreads();
        H[((size_t)(i + 1) * BB + b) * UU + u] = nh;
        C[((size_t)(i + 1) * BB + b) * UU + u] = nc;
    }
}

// ---------------------------------------------------------------------------
// Phase 1 — token L0 / act+dq
// ---------------------------------------------------------------------------
template<bool F32>
__device__ void run_token_l0(int b, const P& p, float* smem, bool is_bw) {
    const int u = threadIdx.x;
    float* s_xh = smem;          // [0,256)=x, [256,512)=h
    const int len = p.token_length[b];
    const void* W0 = is_bw ? p.bw0_W : p.fw0_W;
    const void* b0 = is_bw ? p.bw0_b : p.fw0_b;

    float c0 = 0.f;
    s_xh[256 + u] = 0.f;
    for (int t = 0; t < len; ++t) {
        const int row = is_bw ? (len - 1 - t) : t;
        s_xh[u] = bf2f(p.token_e[((size_t)b * LL + row) * UU + u]);
        __syncthreads();
        const float nh = lstm_step<512, F32>(W0, b0, s_xh, c0);
        p.x1[((size_t)b * LL + row) * 512 + (is_bw ? 256 : 0) + u] = f2bf(nh);
        __syncthreads();
        s_xh[256 + u] = nh;
    }
}

__device__ void run_token_l0_pk(int b, const P& p, float* smem, bool is_bw) {
    const int u = threadIdx.x;
    float* s_xh = smem;
    const int len = p.token_length[b];
    const ushort_t* Wp = is_bw ? p.pk_bw0 : p.pk_fw0;
    const void* b0 = is_bw ? p.bw0_b : p.fw0_b;

    float c0 = 0.f;
    s_xh[256 + u] = 0.f;
    for (int t = 0; t < len; ++t) {
        const int row = is_bw ? (len - 1 - t) : t;
        s_xh[u] = bf2f(p.token_e[((size_t)b * LL + row) * UU + u]);
        __syncthreads();
        const float nh = lstm_step_pk<512>(Wp, b0, s_xh, c0);
        p.x1[((size_t)b * LL + row) * 512 + (is_bw ? 256 : 0) + u] = f2bf(nh);
        __syncthreads();
        s_xh[256 + u] = nh;
    }
}

template<bool F32>
__device__ void run_act_dq(int b, const P& p, float* smem) {
    const int u = threadIdx.x;
    float* s_xh0 = smem;         // [0,512)
    float* s_xh1 = smem + 512;   // [0,512)

    { // act: layout [0,64)=x, [64,320)=h
        const int len = p.history_action_length[b];
        float ca0 = 0.f, ca1 = 0.f, h1last = 0.f;
        s_xh0[ADIM + u] = 0.f;
        s_xh1[256 + u]  = 0.f;
        for (int t = 0; t < len; ++t) {
            const int aid = p.history_action_id[b * AA + t];
            if (u < ADIM) s_xh0[u] = ld1<F32>(p.act_emb, (size_t)aid * ADIM + u);
            __syncthreads();
            const float nh0 = lstm_step<320, F32>(p.act0_W, p.act0_b, s_xh0, ca0);
            __syncthreads();
            s_xh0[ADIM + u] = nh0;
            s_xh1[u]        = nh0;
            __syncthreads();
            const float nh1 = lstm_step<512, F32>(p.act1_W, p.act1_b, s_xh1, ca1);
            __syncthreads();
            s_xh1[256 + u] = nh1;
            h1last = nh1;
        }
        p.act_h[b * UU + u] = h1last;
    }
    __syncthreads();
    { // deque
        const int len = p.deque_length[b];
        float cd0 = 0.f, cd1 = 0.f, h1last = 0.f;
        s_xh0[256 + u] = 0.f;
        s_xh1[256 + u] = 0.f;
        for (int t = 0; t < len; ++t) {
            s_xh0[u] = bf2f(p.deque_e[((size_t)b * DQN + t) * UU + u]);
            __syncthreads();
            const float nh0 = lstm_step<512, F32>(p.dq0_W, p.dq0_b, s_xh0, cd0);
            __syncthreads();
            s_xh0[256 + u] = nh0;
            s_xh1[u]       = nh0;
            __syncthreads();
            const float nh1 = lstm_step<512, F32>(p.dq1_W, p.dq1_b, s_xh1, cd1);
            __syncthreads();
            s_xh1[256 + u] = nh1;
            h1last = nh1;
        }
        p.dq_h[b * UU + u] = h1last;
    }
}

__device__ void run_act_dq_pk(int b, const P& p, float* smem) {
    const int u = threadIdx.x;
    float* s_xh0 = smem;         // [0,512)
    float* s_xh1 = smem + 512;   // [0,512)

    { // act: layout [0,64)=x, [64,320)=h
        const int len = p.history_action_length[b];
        float ca0 = 0.f, ca1 = 0.f, h1last = 0.f;
        s_xh0[ADIM + u] = 0.f;
        s_xh1[256 + u]  = 0.f;
        for (int t = 0; t < len; ++t) {
            const int aid = p.history_action_id[b * AA + t];
            if (u < ADIM) s_xh0[u] = ld1<false>(p.act_emb, (size_t)aid * ADIM + u);
            __syncthreads();
            const float nh0 = lstm_step_pk<320>(p.pk_act0, p.act0_b, s_xh0, ca0);
            __syncthreads();
            s_xh0[ADIM + u] = nh0;
            s_xh1[u]        = nh0;
            __syncthreads();
            const float nh1 = lstm_step_pk<512>(p.pk_act1, p.act1_b, s_xh1, ca1);
            __syncthreads();
            s_xh1[256 + u] = nh1;
            h1last = nh1;
        }
        p.act_h[b * UU + u] = h1last;
    }
    __syncthreads();
    { // deque
        const int len = p.deque_length[b];
        float cd0 = 0.f, cd1 = 0.f, h1last = 0.f;
        s_xh0[256 + u] = 0.f;
        s_xh1[256 + u] = 0.f;
        for (int t = 0; t < len; ++t) {
            s_xh0[u] = bf2f(p.deque_e[((size_t)b * DQN + t) * UU + u]);
            __syncthreads();
            const float nh0 = lstm_step_pk<512>(p.pk_dq0, p.dq0_b, s_xh0, cd0);
            __syncthreads();
            s_xh0[256 + u] = nh0;
            s_xh1[u]       = nh0;
            __syncthreads();
            const float nh1 = lstm_step_pk<512>(p.pk_dq1, p.dq1_b, s_xh1, cd1);
            __syncthreads();
            s_xh1[256 + u] = nh1;
            h1last = nh1;
        }
        p.dq_h[b * UU + u] = h1last;
    }
}

__global__ __launch_bounds__(256) void phase1_kernel(P p) {
    __shared__ __align__(16) float smem[1536];
    const bool f32 = (p.flag[0] == 1);
    const int chain = blockIdx.x & 3;
    const int b     = blockIdx.x >> 2;
    if (f32) {
        if (chain == 0)      run_tree<true>(b, p, smem);
        else if (chain == 1) run_token_l0<true>(b, p, smem, false);
        else if (chain == 2) run_token_l0<true>(b, p, smem, true);
        else                 run_act_dq<true>(b, p, smem);
    } else {
        if (chain == 0)      run_tree_pk(b, p, smem);
        else if (chain == 1) run_token_l0_pk(b, p, smem, false);
        else if (chain == 2) run_token_l0_pk(b, p, smem, true);
        else                 run_act_dq_pk(b, p, smem);
    }
}

// ---------------------------------------------------------------------------
// Phase 2
// ---------------------------------------------------------------------------
template<bool F32>
__device__ void run_stack(int b, const P& p, float* smem) {
    const int u = threadIdx.x;
    float* s_xh0 = smem;         // [0,512)
    float* s_xh1 = smem + 512;   // [0,512)
    const int len = p.stack_length[b];
    float cs0 = 0.f, cs1 = 0.f, h1last = 0.f;
    s_xh0[256 + u] = 0.f;
    s_xh1[256 + u] = 0.f;
    for (int t = 0; t < len; ++t) {
        const int so = p.stack_order[b * SS + t];
        s_xh0[u] = p.H[((size_t)so * BB + b) * UU + u];
        __syncthreads();
        const float nh0 = lstm_step<512, F32>(p.stack0_W, p.stack0_b, s_xh0, cs0);
        __syncthreads();
        s_xh0[256 + u] = nh0;
        s_xh1[u]       = nh0;
        __syncthreads();
        const float nh1 = lstm_step<512, F32>(p.stack1_W, p.stack1_b, s_xh1, cs1);
        __syncthreads();
        s_xh1[256 + u] = nh1;
        h1last = nh1;
    }
    p.stack_h[b * UU + u] = h1last;
}

__device__ void run_stack_pk(int b, const P& p, float* smem) {
    const int u = threadIdx.x;
    float* s_xh0 = smem;         // [0,512)
    float* s_xh1 = smem + 512;   // [0,512)
    const int len = p.stack_length[b];
    float cs0 = 0.f, cs1 = 0.f, h1last = 0.f;
    s_xh0[256 + u] = 0.f;
    s_xh1[256 + u] = 0.f;
    for (int t = 0; t < len; ++t) {
        const int so = p.stack_order[b * SS + t];
        s_xh0[u] = p.H[((size_t)so * BB + b) * UU + u];
        __syncthreads();
        const float nh0 = lstm_step_pk<512>(p.pk_stack0, p.stack0_b, s_xh0, cs0);
        __syncthreads();
        s_xh0[256 + u] = nh0;
        s_xh1[u]       = nh0;
        __syncthreads();
        const float nh1 = lstm_step_pk<512>(p.pk_stack1, p.stack1_b, s_xh1, cs1);
        __syncthreads();
        s_xh1[256 + u] = nh1;
        h1last = nh1;
    }
    p.stack_h[b * UU + u] = h1last;
}

template<bool F32>
__device__ void run_token_l1(int b, const P& p, float* smem, bool is_bw) {
    const int u = threadIdx.x;
    float* s_xh = smem;          // [0,512)=x1 row, [512,768)=h
    const int len  = p.token_length[b];
    const int btop = p.buff_top_id[b];
    const void* W1 = is_bw ? p.bw1_W : p.fw1_W;
    const void* b1 = is_bw ? p.bw1_b : p.fw1_b;

    float c1 = 0.f, hlast = 0.f;
    s_xh[512 + u] = 0.f;
    for (int t = 0; t < len; ++t) {
        const int row = is_bw ? (len - 1 - t) : t;
        const ushort_t* xr = p.x1 + ((size_t)b * LL + row) * 512;
        s_xh[u]       = bf2f(xr[u]);
        s_xh[256 + u] = bf2f(xr[256 + u]);
        __syncthreads();
        const float nh = lstm_step<768, F32>(W1, b1, s_xh, c1);
        if (!is_bw) {
            if (t == btop) p.fw_top[b * UU + u] = nh;
        } else {
            if (t == 0)              p.bw_bottom[b * UU + u] = nh;
            if (t == len - 1 - btop) p.bw_top[b * UU + u]    = nh;
        }
        __syncthreads();
        s_xh[512 + u] = nh;
        hlast = nh;
    }
    if (!is_bw) p.fw1_h[b * UU + u] = hlast;
}

__device__ void run_token_l1_pk(int b, const P& p, float* smem, bool is_bw) {
    const int u = threadIdx.x;
    float* s_xh = smem;          // [0,512)=x1 row, [512,768)=h
    const int len  = p.token_length[b];
    const int btop = p.buff_top_id[b];
    const ushort_t* Wp = is_bw ? p.pk_bw1 : p.pk_fw1;
    const void* b1 = is_bw ? p.bw1_b : p.fw1_b;

    float c1 = 0.f, hlast = 0.f;
    s_xh[512 + u] = 0.f;
    for (int t = 0; t < len; ++t) {
        const int row = is_bw ? (len - 1 - t) : t;
        const ushort_t* xr = p.x1 + ((size_t)b * LL + row) * 512;
        s_xh[u]       = bf2f(xr[u]);
        s_xh[256 + u] = bf2f(xr[256 + u]);
        __syncthreads();
        const float nh = lstm_step_pk<768>(Wp, b1, s_xh, c1);
        if (!is_bw) {
            if (t == btop) p.fw_top[b * UU + u] = nh;
        } else {
            if (t == 0)              p.bw_bottom[b * UU + u] = nh;
            if (t == len - 1 - btop) p.bw_top[b * UU + u]    = nh;
        }
        __syncthreads();
        s_xh[512 + u] = nh;
        hlast = nh;
    }
    if (!is_bw) p.fw1_h[b * UU + u] = hlast;
}

__global__ __launch_bounds__(256) void phase2_kernel(P p) {
    __shared__ __align__(16) float smem[1024];
    const bool f32 = (p.flag[0] == 1);
    const int chain = blockIdx.x % 3;
    const int b     = blockIdx.x / 3;
    if (f32) {
        if (chain == 0)      run_stack<true>(b, p, smem);
        else if (chain == 1) run_token_l1<true>(b, p, smem, false);
        else                 run_token_l1<true>(b, p, smem, true);
    } else {
        if (chain == 0)      run_stack_pk(b, p, smem);
        else if (chain == 1) run_token_l1_pk(b, p, smem, false);
        else                 run_token_l1_pk(b, p, smem, true);
    }
}

// ---------------------------------------------------------------------------
// Final + pipeline tracers
// ---------------------------------------------------------------------------
template<bool F32>
__device__ __forceinline__ void st_out(void* out, int i, float v) {
    if constexpr (F32) reinterpret_cast<float*>(out)[i] = v;
    else               reinterpret_cast<__hip_bfloat16*>(out)[i] = __float2bfloat16(v);
}

template<bool F32>
__device__ void final_impl(const P& p, void* out, float* s_f) {
    const int b = blockIdx.x;
    const int u = threadIdx.x;
    s_f[u]        = p.stack_h[b * UU + u];
    s_f[256 + u]  = p.fw1_h[b * UU + u] - p.fw_top[b * UU + u];
    s_f[512 + u]  = p.bw_top[b * UU + u] - p.bw_bottom[b * UU + u];
    s_f[768 + u]  = p.act_h[b * UU + u];
    s_f[1024 + u] = p.dq_h[b * UU + u];
    __syncthreads();
    if (u < NAOUT) {
        float acc = ld1<F32>(p.fin_b, u);
        for (int r = 0; r < 1280; ++r)
            acc = fmaf(s_f[r], ld1<F32>(p.fin_W, (size_t)r * NAOUT + u), acc);
        acc = fmaxf(acc, 0.f);
        st_out<F32>(out, b * NAOUT + u, acc);
    }
    if (b == 0 && u == 0) {
        const uint_t POIS = 0xAAAAAAAAu;
        const uint_t* te = reinterpret_cast<const uint_t*>(p.tree_e);
        const uint_t* x1 = reinterpret_cast<const uint_t*>(p.x1);
        const uint_t* sh = reinterpret_cast<const uint_t*>(p.stack_h);
        bool te_p = true, x1_p = true;
        for (int i = 0; i < 8; ++i) { te_p &= (te[i] == POIS); x1_p &= (x1[i] == POIS); }
        bool sh_p = (sh[0] == POIS) && (sh[1] == POIS);
        float sent = 0.f;
        if (te_p)      sent = 3000.f;
        else if (x1_p) sent = 4000.f;
        else if (sh_p) sent = 5000.f;
        else if (*reinterpret_cast<const uint_t*>(p.flag) == POIS) sent = 6000.f;
        if (sent > 0.f) st_out<F32>(out, 0, sent);
    }
}

__global__ __launch_bounds__(256) void final_kernel(P p, void* out) {
    __shared__ __align__(16) float s_f[1280];
    if (p.flag[0] == 1) final_impl<true>(p, out, s_f);
    else                final_impl<false>(p, out, s_f);
}

// ---------------------------------------------------------------------------
extern "C" void kernel_launch(void* const* d_in, const int* in_sizes, int n_in,
                              void* d_out, int out_size, void* d_ws, size_t ws_size,
                              hipStream_t stream) {
    if (n_in != 43) {
        sentinel_kernel<<<1, 64, 0, stream>>>(d_out, 9000.f + (float)n_in);
        return;
    }
    if (out_size != NAOUT * BB) {
        sentinel_kernel<<<1, 64, 0, stream>>>(d_out, 8000.f);
        return;
    }

    P p;
    p.tree_word_id          = (const int*)d_in[0];
    p.tree_pos_id           = (const int*)d_in[1];
    p.token_word_id         = (const int*)d_in[2];
    p.token_pos_id          = (const int*)d_in[3];
    p.history_action_id     = (const int*)d_in[4];
    p.buff_top_id           = (const int*)d_in[5];
    p.deque_word_id         = (const int*)d_in[6];
    p.deque_pos_id          = (const int*)d_in[7];
    p.deque_length          = (const int*)d_in[8];
    p.children_order        = (const int*)d_in[9];
    p.stack_order           = (const int*)d_in[10];
    p.stack_length          = (const int*)d_in[11];
    p.token_length          = (const int*)d_in[12];
    p.history_action_length = (const int*)d_in[13];
    p.word_emb = d_in[14];
    p.pos_emb  = d_in[15];
    p.act_emb  = d_in[16];
    p.wd_W     = d_in[17];
    p.wd_b     = d_in[18];
    p.tree_W   = d_in[19];
    p.tree_b   = d_in[20];
    p.stack0_W = d_in[21];
    p.stack0_b = d_in[22];
    p.stack1_W = d_in[23];
    p.stack1_b = d_in[24];
    p.fw0_W    = d_in[25];
    p.fw0_b    = d_in[26];
    p.bw0_W    = d_in[27];
    p.bw0_b    = d_in[28];
    p.fw1_W    = d_in[29];
    p.fw1_b    = d_in[30];
    p.bw1_W    = d_in[31];
    p.bw1_b    = d_in[32];
    p.act0_W   = d_in[33];
    p.act0_b   = d_in[34];
    p.act1_W   = d_in[35];
    p.act1_b   = d_in[36];
    p.dq0_W    = d_in[37];
    p.dq0_b    = d_in[38];
    p.dq1_W    = d_in[39];
    p.dq1_b    = d_in[40];
    p.fin_W    = d_in[41];
    p.fin_b    = d_in[42];

    char* base = (char*)d_ws;
    size_t off = 0;
    p.flag = (int*)(base + off);           off += 16;
    p.stack_h   = (float*)(base + off);    off += (size_t)BB * UU * 4;
    p.fw1_h     = (float*)(base + off);    off += (size_t)BB * UU * 4;
    p.fw_top    = (float*)(base + off);    off += (size_t)BB * UU * 4;
    p.bw_top    = (float*)(base + off);    off += (size_t)BB * UU * 4;
    p.bw_bottom = (float*)(base + off);    off += (size_t)BB * UU * 4;
    p.act_h     = (float*)(base + off);    off += (size_t)BB * UU * 4;
    p.dq_h      = (float*)(base + off);    off += (size_t)BB * UU * 4;
    p.tree_e  = (float*)(base + off);      off += (size_t)BB * TT * UU * 4;   // f32
    p.token_e = (ushort_t*)(base + off);   off += (size_t)BB * LL * UU * 2;
    p.deque_e = (ushort_t*)(base + off);   off += (size_t)BB * DQN * UU * 2;
    p.x1      = (ushort_t*)(base + off);   off += (size_t)BB * LL * 512 * 2;
    p.H       = (float*)(base + off);      off += (size_t)(TT + 1) * BB * UU * 4;
    p.C       = (float*)(base + off);      off += (size_t)(TT + 1) * BB * UU * 4;
    // packed bf16 weights (R*1024 ushorts each)
    p.pk_tree   = (ushort_t*)(base + off); off += (size_t)512 * 1024 * 2;
    p.pk_stack0 = (ushort_t*)(base + off); off += (size_t)512 * 1024 * 2;
    p.pk_stack1 = (ushort_t*)(base + off); off += (size_t)512 * 1024 * 2;
    p.pk_fw0    = (ushort_t*)(base + off); off += (size_t)512 * 1024 * 2;
    p.pk_bw0    = (ushort_t*)(base + off); off += (size_t)512 * 1024 * 2;
    p.pk_fw1    = (ushort_t*)(base + off); off += (size_t)768 * 1024 * 2;
    p.pk_bw1    = (ushort_t*)(base + off); off += (size_t)768 * 1024 * 2;
    p.pk_act0   = (ushort_t*)(base + off); off += (size_t)320 * 1024 * 2;
    p.pk_act1   = (ushort_t*)(base + off); off += (size_t)512 * 1024 * 2;
    p.pk_dq0    = (ushort_t*)(base + off); off += (size_t)512 * 1024 * 2;
    p.pk_dq1    = (ushort_t*)(base + off); off += (size_t)512 * 1024 * 2;
    // ~49.9 MiB

    if (ws_size < off) {
        sentinel_kernel<<<1, 64, 0, stream>>>(d_out, 7000.f + (float)(ws_size >> 20));
        return;
    }

    detect_kernel<<<1, 64, 0, stream>>>((const uint_t*)d_in[14], p.flag);
    pack_kernel<<<dim3(2976), dim3(256), 0, stream>>>(p);
    embed_kernel<<<dim3(BB * TT + BB * LL + BB * DQN), dim3(256), 0, stream>>>(p);
    phase1_kernel<<<dim3(4 * BB), dim3(256), 0, stream>>>(p);
    phase2_kernel<<<dim3(3 * BB), dim3(256), 0, stream>>>(p);
    final_kernel<<<dim3(BB), dim3(256), 0, stream>>>(p, d_out);
}

// Round 2
// 7473.636 us; speedup vs baseline: 1.5395x; 1.5395x over previous
//
#include <hip/hip_runtime.h>
#include <hip/hip_bf16.h>
#include <cstdint>

// Problem constants
#define BB   64
#define TT   128
#define KK   4
#define LL   128
#define SS   64
#define AA   64
#define DQN  32
#define UU   256
#define NAOUT 164
#define WDIM 300
#define PDIM 64
#define ADIM 64

// Packed-weight row offsets (rows of 1024 cols, one float4 per (row,u))
#define OFF_TREE 0
#define OFF_S0   512
#define OFF_S1   1024
#define OFF_FW0  1536
#define OFF_BW0  2048
#define OFF_FW1  2560
#define OFF_BW1  3328
#define OFF_ACT0 4096
#define OFF_ACT1 4416
#define OFF_DQ0  4928
#define OFF_DQ1  5440
#define PK_ROWS  5952

typedef unsigned short ushort_t;
typedef unsigned int   uint_t;

__device__ __forceinline__ float bf2f(ushort_t s) {
    return __uint_as_float(((uint_t)s) << 16);
}
__device__ __forceinline__ ushort_t f2bf(float x) {
    __hip_bfloat16 h = __float2bfloat16(x);
    return *reinterpret_cast<ushort_t*>(&h);
}
__device__ __forceinline__ float sigm(float x) { return 1.0f / (1.0f + expf(-x)); }

// Dual-dtype load: F32=true -> buffer holds float32; false -> bf16.
template<bool F32>
__device__ __forceinline__ float ld1(const void* p_, size_t i) {
    if constexpr (F32) return reinterpret_cast<const float*>(p_)[i];
    else               return bf2f(reinterpret_cast<const ushort_t*>(p_)[i]);
}

struct P {
    // int inputs
    const int *tree_word_id, *tree_pos_id, *token_word_id, *token_pos_id, *history_action_id,
              *buff_top_id, *deque_word_id, *deque_pos_id, *deque_length, *children_order,
              *stack_order, *stack_length, *token_length, *history_action_length;
    // float-family params (dtype resolved at runtime)
    const void *word_emb, *pos_emb, *act_emb, *wd_W, *wd_b, *tree_W, *tree_b,
        *stack0_W, *stack0_b, *stack1_W, *stack1_b, *fw0_W, *fw0_b, *bw0_W, *bw0_b,
        *fw1_W, *fw1_b, *bw1_W, *bw1_b, *act0_W, *act0_b, *act1_W, *act1_b,
        *dq0_W, *dq0_b, *dq1_W, *dq1_b, *fin_W, *fin_b;
    // workspace
    int* flag;                          // [0]: 0 = bf16 world, 1 = f32 world
    float *stack_h, *fw1_h, *fw_top, *bw_top, *bw_bottom, *act_h, *dq_h;  // f32
    float *tree_e;                      // f32 (tree dynamics are chaotic — no bf16 seed)
    ushort_t *token_e, *deque_e, *x1;   // bf16 (contractive chains tolerate rounding)
    float *H, *C;                       // f32
    // Unified packed weights: f32 float4 gate-interleaved, both worlds.
    // pkf[row*256 + u] = {W[row][u], W[row][256+u], W[row][512+u], W[row][768+u]}
    float4* pkf;
};

// ---------------------------------------------------------------------------
// dtype detector (f32 world confirmed round 1 via input-size evidence)
// ---------------------------------------------------------------------------
__global__ void detect_kernel(const uint_t* w, int* flag) {
    __shared__ int cnt;
    if (threadIdx.x == 0) cnt = 0;
    __syncthreads();
    int local = 0;
    for (int i = threadIdx.x; i < 256; i += 64) {
        uint_t lo = w[i] & 0xFFFFu;
        uint_t e  = (lo >> 7) & 0xFFu;
        if (lo == 0u || (e >= 0x6Cu && e <= 0x7Fu)) local++;
    }
    atomicAdd(&cnt, local);
    __syncthreads();
    if (threadIdx.x == 0) flag[0] = (cnt >= 200) ? 0 : 1;
}

__global__ void sentinel_kernel(void* out, float v) {
    if (threadIdx.x == 0) {
        reinterpret_cast<float*>(out)[0] = v;
        reinterpret_cast<__hip_bfloat16*>(out)[2] = __float2bfloat16(v);
    }
}

// ---------------------------------------------------------------------------
// Weight packing: one row per block; emits f32 float4 {g0,g1,g2,g3} per (r,u).
// ---------------------------------------------------------------------------
__global__ __launch_bounds__(256) void pack_kernel(P p) {
    const bool f32 = (p.flag[0] == 1);
    const int rg = blockIdx.x;            // global packed row
    const int u  = threadIdx.x;
    const void* src; int r;
    if      (rg < 512)  { src = p.tree_W;   r = rg; }
    else if (rg < 1024) { src = p.stack0_W; r = rg - 512; }
    else if (rg < 1536) { src = p.stack1_W; r = rg - 1024; }
    else if (rg < 2048) { src = p.fw0_W;    r = rg - 1536; }
    else if (rg < 2560) { src = p.bw0_W;    r = rg - 2048; }
    else if (rg < 3328) { src = p.fw1_W;    r = rg - 2560; }
    else if (rg < 4096) { src = p.bw1_W;    r = rg - 3328; }
    else if (rg < 4416) { src = p.act0_W;   r = rg - 4096; }
    else if (rg < 4928) { src = p.act1_W;   r = rg - 4416; }
    else if (rg < 5440) { src = p.dq0_W;    r = rg - 4928; }
    else                { src = p.dq1_W;    r = rg - 5440; }
    const size_t ro = (size_t)r * 1024;
    float4 v;
    if (f32) {
        const float* s = reinterpret_cast<const float*>(src) + ro;
        v = make_float4(s[u], s[256 + u], s[512 + u], s[768 + u]);
    } else {
        const ushort_t* s = reinterpret_cast<const ushort_t*>(src) + ro;
        v = make_float4(bf2f(s[u]), bf2f(s[256 + u]), bf2f(s[512 + u]), bf2f(s[768 + u]));
    }
    p.pkf[(size_t)rg * 256 + u] = v;
}

// ---------------------------------------------------------------------------
// Embedding (one row per block): e = relu(concat(word_emb[wid], pos_emb[pid]) @ wd_W + wd_b)
// Tree rows -> f32 output; token/deque rows -> bf16 output.
// ---------------------------------------------------------------------------
template<bool F32>
__device__ void embed_impl(const P& p, float* s_e) {
    const int u   = threadIdx.x;
    const int row = blockIdx.x;

    const int* wid; const int* pid; int rowbase; int which;
    float* out_f = nullptr; ushort_t* out_b = nullptr;
    if (row < BB * TT) {
        wid = p.tree_word_id; pid = p.tree_pos_id; rowbase = row; which = 0;
        out_f = p.tree_e;
    } else if (row < BB * TT + BB * LL) {
        wid = p.token_word_id; pid = p.token_pos_id; rowbase = row - BB * TT; which = 1;
        out_b = p.token_e;
    } else {
        wid = p.deque_word_id; pid = p.deque_pos_id; rowbase = row - BB * TT - BB * LL; which = 2;
        out_b = p.deque_e;
    }

    const int w  = wid[rowbase];
    const int pp = pid[rowbase];
    for (int e = u; e < WDIM + PDIM; e += 256) {
        s_e[e] = (e < WDIM) ? ld1<F32>(p.word_emb, (size_t)w * WDIM + e)
                            : ld1<F32>(p.pos_emb, (size_t)pp * PDIM + (e - WDIM));
    }
    __syncthreads();

    float acc = ld1<F32>(p.wd_b, u);
    for (int r = 0; r < WDIM + PDIM; ++r)
        acc = fmaf(s_e[r], ld1<F32>(p.wd_W, (size_t)r * UU + u), acc);
    acc = fmaxf(acc, 0.f);
    if (which == 0) out_f[(size_t)rowbase * UU + u] = acc;
    else            out_b[(size_t)rowbase * UU + u] = f2bf(acc);
}

__global__ __launch_bounds__(256) void embed_kernel(P p) {
    __shared__ __align__(16) float s_e[384];
    if (p.flag[0] == 1) embed_impl<true>(p, s_e);
    else                embed_impl<false>(p, s_e);
}

// ---------------------------------------------------------------------------
// One LSTM step over packed f32 float4 weights. Thread u owns unit u.
// Wp = pkf + OFF*256 + u. bz = {b_i, b_j, b_f + 1.0, b_o}.
// 16-deep explicit load staging => 16 dwordx4 in flight per wave.
// ---------------------------------------------------------------------------
template<int R>
__device__ __forceinline__ float lstm_step_f4(const float4* __restrict__ Wp,
                                              const float4 bz,
                                              const float* __restrict__ s_xh,
                                              float& c) {
    float zi = bz.x, zj = bz.y, zf = bz.z, zo = bz.w;
    for (int r0 = 0; r0 < R; r0 += 16) {
        float4 w[16];
        #pragma unroll
        for (int k = 0; k < 16; ++k) w[k] = Wp[(size_t)(r0 + k) * 256];
        #pragma unroll
        for (int q = 0; q < 4; ++q) {
            const float4 x4 = *reinterpret_cast<const float4*>(s_xh + r0 + 4 * q);
            const float xv[4] = {x4.x, x4.y, x4.z, x4.w};
            #pragma unroll
            for (int j = 0; j < 4; ++j) {
                const float4 wv = w[4 * q + j];
                zi = fmaf(xv[j], wv.x, zi);
                zj = fmaf(xv[j], wv.y, zj);
                zf = fmaf(xv[j], wv.z, zf);
                zo = fmaf(xv[j], wv.w, zo);
            }
        }
    }
    const float nc = c * sigm(zf) + sigm(zi) * tanhf(zj);
    c = nc;
    return tanhf(nc) * sigm(zo);
}

template<bool F32>
__device__ __forceinline__ float4 load_bias4(const void* b, int u) {
    // gates i|j|f|o at cols u, 256+u, 512+u, 768+u; forget bias folded in.
    return make_float4(ld1<F32>(b, u), ld1<F32>(b, 256 + u),
                       ld1<F32>(b, 512 + u) + 1.0f, ld1<F32>(b, 768 + u));
}

// ---------------------------------------------------------------------------
// Phase 1 — tree (gates i|j|o|f: f column is [768,1024))
// ---------------------------------------------------------------------------
template<bool F32>
__device__ void run_tree_f4(int b, const P& p, float* smem) {
    const int u = threadIdx.x;
    float* s_x  = smem;          // 256
    float* s_hj = smem + 256;    // 256
    float* s_hk = smem + 512;    // 1024
    float* H = p.H;
    float* C = p.C;
    H[(size_t)b * UU + u] = 0.f;
    C[(size_t)b * UU + u] = 0.f;

    const float4* __restrict__ Wt = p.pkf + (size_t)OFF_TREE * 256 + u;   // x rows [0,256)
    const float4* __restrict__ Wh = Wt + (size_t)256 * 256;               // h rows [256,512)
    const float bi = ld1<F32>(p.tree_b, u);
    const float bj = ld1<F32>(p.tree_b, 256 + u);
    const float bo = ld1<F32>(p.tree_b, 512 + u);
    const float bf = ld1<F32>(p.tree_b, 768 + u) + 1.0f;

    for (int i = 0; i < TT; ++i) {
        const int* co = p.children_order + ((size_t)b * TT + i) * KK;
        const int i0 = co[0], i1 = co[1], i2 = co[2], i3 = co[3];
        const float h0 = H[((size_t)i0 * BB + b) * UU + u];
        const float h1 = H[((size_t)i1 * BB + b) * UU + u];
        const float h2 = H[((size_t)i2 * BB + b) * UU + u];
        const float h3 = H[((size_t)i3 * BB + b) * UU + u];
        const float c0 = C[((size_t)i0 * BB + b) * UU + u];
        const float c1 = C[((size_t)i1 * BB + b) * UU + u];
        const float c2 = C[((size_t)i2 * BB + b) * UU + u];
        const float c3 = C[((size_t)i3 * BB + b) * UU + u];
        s_x[u]        = p.tree_e[((size_t)b * TT + i) * UU + u];
        s_hk[u]       = h0;
        s_hk[256 + u] = h1;
        s_hk[512 + u] = h2;
        s_hk[768 + u] = h3;
        s_hj[u]       = h0 + h1 + h2 + h3;
        __syncthreads();

        float zi = bi, zj = bj, zo = bo, fx = bf;
        for (int r0 = 0; r0 < 256; r0 += 16) {        // x rows
            float4 w[16];
            #pragma unroll
            for (int k = 0; k < 16; ++k) w[k] = Wt[(size_t)(r0 + k) * 256];
            #pragma unroll
            for (int q = 0; q < 4; ++q) {
                const float4 x4 = *reinterpret_cast<const float4*>(s_x + r0 + 4 * q);
                const float xv[4] = {x4.x, x4.y, x4.z, x4.w};
                #pragma unroll
                for (int j = 0; j < 4; ++j) {
                    const float4 wv = w[4 * q + j];
                    zi = fmaf(xv[j], wv.x, zi);
                    zj = fmaf(xv[j], wv.y, zj);
                    zo = fmaf(xv[j], wv.z, zo);
                    fx = fmaf(xv[j], wv.w, fx);
                }
            }
        }
        float f0 = 0.f, f1 = 0.f, f2 = 0.f, f3 = 0.f;
        for (int r0 = 0; r0 < 256; r0 += 16) {        // h rows
            float4 w[16];
            #pragma unroll
            for (int k = 0; k < 16; ++k) w[k] = Wh[(size_t)(r0 + k) * 256];
            #pragma unroll
            for (int q = 0; q < 4; ++q) {
                const int r = r0 + 4 * q;
                const float4 hj4 = *reinterpret_cast<const float4*>(s_hj + r);
                const float4 a0  = *reinterpret_cast<const float4*>(s_hk + r);
                const float4 a1  = *reinterpret_cast<const float4*>(s_hk + 256 + r);
                const float4 a2  = *reinterpret_cast<const float4*>(s_hk + 512 + r);
                const float4 a3  = *reinterpret_cast<const float4*>(s_hk + 768 + r);
                const float hjv[4] = {hj4.x, hj4.y, hj4.z, hj4.w};
                const float k0[4]  = {a0.x, a0.y, a0.z, a0.w};
                const float k1[4]  = {a1.x, a1.y, a1.z, a1.w};
                const float k2[4]  = {a2.x, a2.y, a2.z, a2.w};
                const float k3[4]  = {a3.x, a3.y, a3.z, a3.w};
                #pragma unroll
                for (int j = 0; j < 4; ++j) {
                    const float4 wv = w[4 * q + j];
                    zi = fmaf(hjv[j], wv.x, zi);
                    zj = fmaf(hjv[j], wv.y, zj);
                    zo = fmaf(hjv[j], wv.z, zo);
                    f0 = fmaf(k0[j], wv.w, f0);
                    f1 = fmaf(k1[j], wv.w, f1);
                    f2 = fmaf(k2[j], wv.w, f2);
                    f3 = fmaf(k3[j], wv.w, f3);
                }
            }
        }
        const float fsum = c0 * sigm(fx + f0) + c1 * sigm(fx + f1)
                         + c2 * sigm(fx + f2) + c3 * sigm(fx + f3);
        const float nc = fsum + sigm(zi) * tanhf(zj);
        const float nh = tanhf(nc) * sigm(zo);
        __syncthreads();
        H[((size_t)(i + 1) * BB + b) * UU + u] = nh;
        C[((size_t)(i + 1) * BB + b) * UU + u] = nc;
    }
}

// ---------------------------------------------------------------------------
// Phase 1 — token L0 / act+dq
// ---------------------------------------------------------------------------
template<bool F32>
__device__ void run_token_l0_f4(int b, const P& p, float* smem, bool is_bw) {
    const int u = threadIdx.x;
    float* s_xh = smem;          // [0,256)=x, [256,512)=h
    const int len = p.token_length[b];
    const float4* __restrict__ Wp = p.pkf + (size_t)(is_bw ? OFF_BW0 : OFF_FW0) * 256 + u;
    const float4 bz = load_bias4<F32>(is_bw ? p.bw0_b : p.fw0_b, u);

    float c0 = 0.f;
    s_xh[256 + u] = 0.f;
    for (int t = 0; t < len; ++t) {
        const int row = is_bw ? (len - 1 - t) : t;
        s_xh[u] = bf2f(p.token_e[((size_t)b * LL + row) * UU + u]);
        __syncthreads();
        const float nh = lstm_step_f4<512>(Wp, bz, s_xh, c0);
        p.x1[((size_t)b * LL + row) * 512 + (is_bw ? 256 : 0) + u] = f2bf(nh);
        __syncthreads();
        s_xh[256 + u] = nh;
    }
}

template<bool F32>
__device__ void run_act_dq_f4(int b, const P& p, float* smem) {
    const int u = threadIdx.x;
    float* s_xh0 = smem;         // [0,512)
    float* s_xh1 = smem + 512;   // [0,512)

    { // act: layout [0,64)=x, [64,320)=h
        const int len = p.history_action_length[b];
        const float4* __restrict__ W0 = p.pkf + (size_t)OFF_ACT0 * 256 + u;
        const float4* __restrict__ W1 = p.pkf + (size_t)OFF_ACT1 * 256 + u;
        const float4 bz0 = load_bias4<F32>(p.act0_b, u);
        const float4 bz1 = load_bias4<F32>(p.act1_b, u);
        float ca0 = 0.f, ca1 = 0.f, h1last = 0.f;
        s_xh0[ADIM + u] = 0.f;
        s_xh1[256 + u]  = 0.f;
        for (int t = 0; t < len; ++t) {
            const int aid = p.history_action_id[b * AA + t];
            if (u < ADIM) s_xh0[u] = ld1<F32>(p.act_emb, (size_t)aid * ADIM + u);
            __syncthreads();
            const float nh0 = lstm_step_f4<320>(W0, bz0, s_xh0, ca0);
            __syncthreads();
            s_xh0[ADIM + u] = nh0;
            s_xh1[u]        = nh0;
            __syncthreads();
            const float nh1 = lstm_step_f4<512>(W1, bz1, s_xh1, ca1);
            __syncthreads();
            s_xh1[256 + u] = nh1;
            h1last = nh1;
        }
        p.act_h[b * UU + u] = h1last;
    }
    __syncthreads();
    { // deque
        const int len = p.deque_length[b];
        const float4* __restrict__ W0 = p.pkf + (size_t)OFF_DQ0 * 256 + u;
        const float4* __restrict__ W1 = p.pkf + (size_t)OFF_DQ1 * 256 + u;
        const float4 bz0 = load_bias4<F32>(p.dq0_b, u);
        const float4 bz1 = load_bias4<F32>(p.dq1_b, u);
        float cd0 = 0.f, cd1 = 0.f, h1last = 0.f;
        s_xh0[256 + u] = 0.f;
        s_xh1[256 + u] = 0.f;
        for (int t = 0; t < len; ++t) {
            s_xh0[u] = bf2f(p.deque_e[((size_t)b * DQN + t) * UU + u]);
            __syncthreads();
            const float nh0 = lstm_step_f4<512>(W0, bz0, s_xh0, cd0);
            __syncthreads();
            s_xh0[256 + u] = nh0;
            s_xh1[u]       = nh0;
            __syncthreads();
            const float nh1 = lstm_step_f4<512>(W1, bz1, s_xh1, cd1);
            __syncthreads();
            s_xh1[256 + u] = nh1;
            h1last = nh1;
        }
        p.dq_h[b * UU + u] = h1last;
    }
}

__global__ __launch_bounds__(256) void phase1_kernel(P p) {
    __shared__ __align__(16) float smem[1536];
    const bool f32 = (p.flag[0] == 1);
    const int chain = blockIdx.x & 3;
    const int b     = blockIdx.x >> 2;
    if (f32) {
        if (chain == 0)      run_tree_f4<true>(b, p, smem);
        else if (chain == 1) run_token_l0_f4<true>(b, p, smem, false);
        else if (chain == 2) run_token_l0_f4<true>(b, p, smem, true);
        else                 run_act_dq_f4<true>(b, p, smem);
    } else {
        if (chain == 0)      run_tree_f4<false>(b, p, smem);
        else if (chain == 1) run_token_l0_f4<false>(b, p, smem, false);
        else if (chain == 2) run_token_l0_f4<false>(b, p, smem, true);
        else                 run_act_dq_f4<false>(b, p, smem);
    }
}

// ---------------------------------------------------------------------------
// Phase 2
// ---------------------------------------------------------------------------
template<bool F32>
__device__ void run_stack_f4(int b, const P& p, float* smem) {
    const int u = threadIdx.x;
    float* s_xh0 = smem;         // [0,512)
    float* s_xh1 = smem + 512;   // [0,512)
    const int len = p.stack_length[b];
    const float4* __restrict__ W0 = p.pkf + (size_t)OFF_S0 * 256 + u;
    const float4* __restrict__ W1 = p.pkf + (size_t)OFF_S1 * 256 + u;
    const float4 bz0 = load_bias4<F32>(p.stack0_b, u);
    const float4 bz1 = load_bias4<F32>(p.stack1_b, u);
    float cs0 = 0.f, cs1 = 0.f, h1last = 0.f;
    s_xh0[256 + u] = 0.f;
    s_xh1[256 + u] = 0.f;
    for (int t = 0; t < len; ++t) {
        const int so = p.stack_order[b * SS + t];
        s_xh0[u] = p.H[((size_t)so * BB + b) * UU + u];
        __syncthreads();
        const float nh0 = lstm_step_f4<512>(W0, bz0, s_xh0, cs0);
        __syncthreads();
        s_xh0[256 + u] = nh0;
        s_xh1[u]       = nh0;
        __syncthreads();
        const float nh1 = lstm_step_f4<512>(W1, bz1, s_xh1, cs1);
        __syncthreads();
        s_xh1[256 + u] = nh1;
        h1last = nh1;
    }
    p.stack_h[b * UU + u] = h1last;
}

template<bool F32>
__device__ void run_token_l1_f4(int b, const P& p, float* smem, bool is_bw) {
    const int u = threadIdx.x;
    float* s_xh = smem;          // [0,512)=x1 row, [512,768)=h
    const int len  = p.token_length[b];
    const int btop = p.buff_top_id[b];
    const float4* __restrict__ Wp = p.pkf + (size_t)(is_bw ? OFF_BW1 : OFF_FW1) * 256 + u;
    const float4 bz = load_bias4<F32>(is_bw ? p.bw1_b : p.fw1_b, u);

    float c1 = 0.f, hlast = 0.f;
    s_xh[512 + u] = 0.f;
    for (int t = 0; t < len; ++t) {
        const int row = is_bw ? (len - 1 - t) : t;
        const ushort_t* xr = p.x1 + ((size_t)b * LL + row) * 512;
        s_xh[u]       = bf2f(xr[u]);
        s_xh[256 + u] = bf2f(xr[256 + u]);
        __syncthreads();
        const float nh = lstm_step_f4<768>(Wp, bz, s_xh, c1);
        if (!is_bw) {
            if (t == btop) p.fw_top[b * UU + u] = nh;
        } else {
            if (t == 0)              p.bw_bottom[b * UU + u] = nh;
            if (t == len - 1 - btop) p.bw_top[b * UU + u]    = nh;
        }
        __syncthreads();
        s_xh[512 + u] = nh;
        hlast = nh;
    }
    if (!is_bw) p.fw1_h[b * UU + u] = hlast;
}

__global__ __launch_bounds__(256) void phase2_kernel(P p) {
    __shared__ __align__(16) float smem[1024];
    const bool f32 = (p.flag[0] == 1);
    const int chain = blockIdx.x % 3;
    const int b     = blockIdx.x / 3;
    if (f32) {
        if (chain == 0)      run_stack_f4<true>(b, p, smem);
        else if (chain == 1) run_token_l1_f4<true>(b, p, smem, false);
        else                 run_token_l1_f4<true>(b, p, smem, true);
    } else {
        if (chain == 0)      run_stack_f4<false>(b, p, smem);
        else if (chain == 1) run_token_l1_f4<false>(b, p, smem, false);
        else                 run_token_l1_f4<false>(b, p, smem, true);
    }
}

// ---------------------------------------------------------------------------
// Final + pipeline tracers
// ---------------------------------------------------------------------------
template<bool F32>
__device__ __forceinline__ void st_out(void* out, int i, float v) {
    if constexpr (F32) reinterpret_cast<float*>(out)[i] = v;
    else               reinterpret_cast<__hip_bfloat16*>(out)[i] = __float2bfloat16(v);
}

template<bool F32>
__device__ void final_impl(const P& p, void* out, float* s_f) {
    const int b = blockIdx.x;
    const int u = threadIdx.x;
    s_f[u]        = p.stack_h[b * UU + u];
    s_f[256 + u]  = p.fw1_h[b * UU + u] - p.fw_top[b * UU + u];
    s_f[512 + u]  = p.bw_top[b * UU + u] - p.bw_bottom[b * UU + u];
    s_f[768 + u]  = p.act_h[b * UU + u];
    s_f[1024 + u] = p.dq_h[b * UU + u];
    __syncthreads();
    if (u < NAOUT) {
        float acc = ld1<F32>(p.fin_b, u);
        for (int r = 0; r < 1280; ++r)
            acc = fmaf(s_f[r], ld1<F32>(p.fin_W, (size_t)r * NAOUT + u), acc);
        acc = fmaxf(acc, 0.f);
        st_out<F32>(out, b * NAOUT + u, acc);
    }
    if (b == 0 && u == 0) {
        const uint_t POIS = 0xAAAAAAAAu;
        const uint_t* te = reinterpret_cast<const uint_t*>(p.tree_e);
        const uint_t* x1 = reinterpret_cast<const uint_t*>(p.x1);
        const uint_t* sh = reinterpret_cast<const uint_t*>(p.stack_h);
        bool te_p = true, x1_p = true;
        for (int i = 0; i < 8; ++i) { te_p &= (te[i] == POIS); x1_p &= (x1[i] == POIS); }
        bool sh_p = (sh[0] == POIS) && (sh[1] == POIS);
        float sent = 0.f;
        if (te_p)      sent = 3000.f;
        else if (x1_p) sent = 4000.f;
        else if (sh_p) sent = 5000.f;
        else if (*reinterpret_cast<const uint_t*>(p.flag) == POIS) sent = 6000.f;
        if (sent > 0.f) st_out<F32>(out, 0, sent);
    }
}

__global__ __launch_bounds__(256) void final_kernel(P p, void* out) {
    __shared__ __align__(16) float s_f[1280];
    if (p.flag[0] == 1) final_impl<true>(p, out, s_f);
    else                final_impl<false>(p, out, s_f);
}

// ---------------------------------------------------------------------------
extern "C" void kernel_launch(void* const* d_in, const int* in_sizes, int n_in,
                              void* d_out, int out_size, void* d_ws, size_t ws_size,
                              hipStream_t stream) {
    if (n_in != 43) {
        sentinel_kernel<<<1, 64, 0, stream>>>(d_out, 9000.f + (float)n_in);
        return;
    }
    if (out_size != NAOUT * BB) {
        sentinel_kernel<<<1, 64, 0, stream>>>(d_out, 8000.f);
        return;
    }

    P p;
    p.tree_word_id          = (const int*)d_in[0];
    p.tree_pos_id           = (const int*)d_in[1];
    p.token_word_id         = (const int*)d_in[2];
    p.token_pos_id          = (const int*)d_in[3];
    p.history_action_id     = (const int*)d_in[4];
    p.buff_top_id           = (const int*)d_in[5];
    p.deque_word_id         = (const int*)d_in[6];
    p.deque_pos_id          = (const int*)d_in[7];
    p.deque_length          = (const int*)d_in[8];
    p.children_order        = (const int*)d_in[9];
    p.stack_order           = (const int*)d_in[10];
    p.stack_length          = (const int*)d_in[11];
    p.token_length          = (const int*)d_in[12];
    p.history_action_length = (const int*)d_in[13];
    p.word_emb = d_in[14];
    p.pos_emb  = d_in[15];
    p.act_emb  = d_in[16];
    p.wd_W     = d_in[17];
    p.wd_b     = d_in[18];
    p.tree_W   = d_in[19];
    p.tree_b   = d_in[20];
    p.stack0_W = d_in[21];
    p.stack0_b = d_in[22];
    p.stack1_W = d_in[23];
    p.stack1_b = d_in[24];
    p.fw0_W    = d_in[25];
    p.fw0_b    = d_in[26];
    p.bw0_W    = d_in[27];
    p.bw0_b    = d_in[28];
    p.fw1_W    = d_in[29];
    p.fw1_b    = d_in[30];
    p.bw1_W    = d_in[31];
    p.bw1_b    = d_in[32];
    p.act0_W   = d_in[33];
    p.act0_b   = d_in[34];
    p.act1_W   = d_in[35];
    p.act1_b   = d_in[36];
    p.dq0_W    = d_in[37];
    p.dq0_b    = d_in[38];
    p.dq1_W    = d_in[39];
    p.dq1_b    = d_in[40];
    p.fin_W    = d_in[41];
    p.fin_b    = d_in[42];

    char* base = (char*)d_ws;
    size_t off = 0;
    p.flag = (int*)(base + off);           off += 16;
    p.stack_h   = (float*)(base + off);    off += (size_t)BB * UU * 4;
    p.fw1_h     = (float*)(base + off);    off += (size_t)BB * UU * 4;
    p.fw_top    = (float*)(base + off);    off += (size_t)BB * UU * 4;
    p.bw_top    = (float*)(base + off);    off += (size_t)BB * UU * 4;
    p.bw_bottom = (float*)(base + off);    off += (size_t)BB * UU * 4;
    p.act_h     = (float*)(base + off);    off += (size_t)BB * UU * 4;
    p.dq_h      = (float*)(base + off);    off += (size_t)BB * UU * 4;
    p.tree_e  = (float*)(base + off);      off += (size_t)BB * TT * UU * 4;   // f32
    p.token_e = (ushort_t*)(base + off);   off += (size_t)BB * LL * UU * 2;
    p.deque_e = (ushort_t*)(base + off);   off += (size_t)BB * DQN * UU * 2;
    p.x1      = (ushort_t*)(base + off);   off += (size_t)BB * LL * 512 * 2;
    p.H       = (float*)(base + off);      off += (size_t)(TT + 1) * BB * UU * 4;
    p.C       = (float*)(base + off);      off += (size_t)(TT + 1) * BB * UU * 4;
    p.pkf     = (float4*)(base + off);     off += (size_t)PK_ROWS * 256 * 16;  // 24.4 MiB
    // total ~62 MiB

    if (ws_size < off) {
        sentinel_kernel<<<1, 64, 0, stream>>>(d_out, 7000.f + (float)(ws_size >> 20));
        return;
    }

    detect_kernel<<<1, 64, 0, stream>>>((const uint_t*)d_in[14], p.flag);
    pack_kernel<<<dim3(PK_ROWS), dim3(256), 0, stream>>>(p);
    embed_kernel<<<dim3(BB * TT + BB * LL + BB * DQN), dim3(256), 0, stream>>>(p);
    phase1_kernel<<<dim3(4 * BB), dim3(256), 0, stream>>>(p);
    phase2_kernel<<<dim3(3 * BB), dim3(256), 0, stream>>>(p);
    final_kernel<<<dim3(BB), dim3(256), 0, stream>>>(p, d_out);
}

// Round 4
// 6335.577 us; speedup vs baseline: 1.8160x; 1.1796x over previous
//
#include <hip/hip_runtime.h>
#include <hip/hip_bf16.h>
#include <hip/hip_fp16.h>
#include <cstdint>

// Problem constants
#define BB   64
#define TT   128
#define KK   4
#define LL   128
#define SS   64
#define AA   64
#define DQN  32
#define UU   256
#define NAOUT 164
#define WDIM 300
#define PDIM 64
#define ADIM 64

// ---- Fallback (round-2) full-pack row offsets ----
#define OFF_TREE 0
#define OFF_S0   512
#define OFF_S1   1024
#define OFF_FW0  1536
#define OFF_BW0  2048
#define OFF_FW1  2560
#define OFF_BW1  3328
#define OFF_ACT0 4096
#define OFF_ACT1 4416
#define OFF_DQ0  4928
#define OFF_DQ1  5440
#define PK_ROWS_FB 5952

// ---- Plan-B pack: tree full (512 rows) + h-rows only for the rest ----
#define PKH_FW0  512
#define PKH_BW0  768
#define PKH_FW1  1024
#define PKH_BW1  1280
#define PKH_S0   1536
#define PKH_S1   1792
#define PKH_ACT0 2048
#define PKH_ACT1 2304
#define PKH_DQ0  2560
#define PKH_DQ1  2816
#define PK_ROWS_B 3072

typedef unsigned short ushort_t;
typedef unsigned int   uint_t;

__device__ __forceinline__ float bf2f(ushort_t s) {
    return __uint_as_float(((uint_t)s) << 16);
}
__device__ __forceinline__ ushort_t f2bf(float x) {
    __hip_bfloat16 h = __float2bfloat16(x);
    return *reinterpret_cast<ushort_t*>(&h);
}
__device__ __forceinline__ float sigm(float x) { return 1.0f / (1.0f + expf(-x)); }

__device__ __forceinline__ uint_t pack2h(float a, float b) {
    __half2 h = __floats2half2_rn(a, b);
    return *reinterpret_cast<uint_t*>(&h);
}
__device__ __forceinline__ float2 unp2h(uint_t v) {
    __half2 h = *reinterpret_cast<__half2*>(&v);
    return __half22float2(h);
}

// Dual-dtype load: F32=true -> buffer holds float32; false -> bf16.
template<bool F32>
__device__ __forceinline__ float ld1(const void* p_, size_t i) {
    if constexpr (F32) return reinterpret_cast<const float*>(p_)[i];
    else               return bf2f(reinterpret_cast<const ushort_t*>(p_)[i]);
}

struct P {
    // int inputs
    const int *tree_word_id, *tree_pos_id, *token_word_id, *token_pos_id, *history_action_id,
              *buff_top_id, *deque_word_id, *deque_pos_id, *deque_length, *children_order,
              *stack_order, *stack_length, *token_length, *history_action_length;
    // float-family params (dtype resolved at runtime)
    const void *word_emb, *pos_emb, *act_emb, *wd_W, *wd_b, *tree_W, *tree_b,
        *stack0_W, *stack0_b, *stack1_W, *stack1_b, *fw0_W, *fw0_b, *bw0_W, *bw0_b,
        *fw1_W, *fw1_b, *bw1_W, *bw1_b, *act0_W, *act0_b, *act1_W, *act1_b,
        *dq0_W, *dq0_b, *dq1_W, *dq1_b, *fin_W, *fin_b;
    // workspace
    int* flag;                          // [0]: 0 = bf16 world, 1 = f32 world
    float *stack_h, *fw1_h, *fw_top, *bw_top, *bw_bottom, *act_h, *dq_h;  // f32
    float *tree_e;                      // f32 (tree dynamics chaotic — stays f32 end-to-end)
    ushort_t *token_e, *deque_e, *x1;   // bf16
    float *H, *C;                       // f32
    float *a0_seq, *d0_seq, *s0_seq;    // f32 layer-0 h sequences (plan B)
    // zx buffers: fp16x4 per (n, unit): x-part of gate preactivations incl. bias (+forget bias)
    uint2 *zxA, *zxB, *zxC, *zxD, *zxS;
    // packed weights: float4 {g0,g1,g2,g3} per (row, u)
    float4* pkf;
};

// ---------------------------------------------------------------------------
// dtype detector
// ---------------------------------------------------------------------------
__global__ void detect_kernel(const uint_t* w, int* flag) {
    __shared__ int cnt;
    if (threadIdx.x == 0) cnt = 0;
    __syncthreads();
    int local = 0;
    for (int i = threadIdx.x; i < 256; i += 64) {
        uint_t lo = w[i] & 0xFFFFu;
        uint_t e  = (lo >> 7) & 0xFFu;
        if (lo == 0u || (e >= 0x6Cu && e <= 0x7Fu)) local++;
    }
    atomicAdd(&cnt, local);
    __syncthreads();
    if (threadIdx.x == 0) flag[0] = (cnt >= 200) ? 0 : 1;
}

__global__ void sentinel_kernel(void* out, float v) {
    if (threadIdx.x == 0) {
        reinterpret_cast<float*>(out)[0] = v;
        reinterpret_cast<__hip_bfloat16*>(out)[2] = __float2bfloat16(v);
    }
}

// ---------------------------------------------------------------------------
// Weight packing — fallback (full rows)
// ---------------------------------------------------------------------------
__global__ __launch_bounds__(256) void pack_fb_kernel(P p) {
    const bool f32 = (p.flag[0] == 1);
    const int rg = blockIdx.x;
    const int u  = threadIdx.x;
    const void* src; int r;
    if      (rg < 512)  { src = p.tree_W;   r = rg; }
    else if (rg < 1024) { src = p.stack0_W; r = rg - 512; }
    else if (rg < 1536) { src = p.stack1_W; r = rg - 1024; }
    else if (rg < 2048) { src = p.fw0_W;    r = rg - 1536; }
    else if (rg < 2560) { src = p.bw0_W;    r = rg - 2048; }
    else if (rg < 3328) { src = p.fw1_W;    r = rg - 2560; }
    else if (rg < 4096) { src = p.bw1_W;    r = rg - 3328; }
    else if (rg < 4416) { src = p.act0_W;   r = rg - 4096; }
    else if (rg < 4928) { src = p.act1_W;   r = rg - 4416; }
    else if (rg < 5440) { src = p.dq0_W;    r = rg - 4928; }
    else                { src = p.dq1_W;    r = rg - 5440; }
    const size_t ro = (size_t)r * 1024;
    float4 v;
    if (f32) {
        const float* s = reinterpret_cast<const float*>(src) + ro;
        v = make_float4(s[u], s[256 + u], s[512 + u], s[768 + u]);
    } else {
        const ushort_t* s = reinterpret_cast<const ushort_t*>(src) + ro;
        v = make_float4(bf2f(s[u]), bf2f(s[256 + u]), bf2f(s[512 + u]), bf2f(s[768 + u]));
    }
    p.pkf[(size_t)rg * 256 + u] = v;
}

// ---------------------------------------------------------------------------
// Weight packing — plan B (tree full + h-rows only)
// ---------------------------------------------------------------------------
__global__ __launch_bounds__(256) void pack_h_kernel(P p) {
    const bool f32 = (p.flag[0] == 1);
    const int rg = blockIdx.x;
    const int u  = threadIdx.x;
    const void* src; int r;
    if      (rg < 512)  { src = p.tree_W;   r = rg; }
    else if (rg < 768)  { src = p.fw0_W;    r = 256 + rg - 512; }
    else if (rg < 1024) { src = p.bw0_W;    r = 256 + rg - 768; }
    else if (rg < 1280) { src = p.fw1_W;    r = 512 + rg - 1024; }
    else if (rg < 1536) { src = p.bw1_W;    r = 512 + rg - 1280; }
    else if (rg < 1792) { src = p.stack0_W; r = 256 + rg - 1536; }
    else if (rg < 2048) { src = p.stack1_W; r = 256 + rg - 1792; }
    else if (rg < 2304) { src = p.act0_W;   r = 64  + rg - 2048; }
    else if (rg < 2560) { src = p.act1_W;   r = 256 + rg - 2304; }
    else if (rg < 2816) { src = p.dq0_W;    r = 256 + rg - 2560; }
    else                { src = p.dq1_W;    r = 256 + rg - 2816; }
    const size_t ro = (size_t)r * 1024;
    float4 v;
    if (f32) {
        const float* s = reinterpret_cast<const float*>(src) + ro;
        v = make_float4(s[u], s[256 + u], s[512 + u], s[768 + u]);
    } else {
        const ushort_t* s = reinterpret_cast<const ushort_t*>(src) + ro;
        v = make_float4(bf2f(s[u]), bf2f(s[256 + u]), bf2f(s[512 + u]), bf2f(s[768 + u]));
    }
    p.pkf[(size_t)rg * 256 + u] = v;
}

// ---------------------------------------------------------------------------
// Embedding
// ---------------------------------------------------------------------------
template<bool F32>
__device__ void embed_impl(const P& p, float* s_e) {
    const int u   = threadIdx.x;
    const int row = blockIdx.x;

    const int* wid; const int* pid; int rowbase; int which;
    float* out_f = nullptr; ushort_t* out_b = nullptr;
    if (row < BB * TT) {
        wid = p.tree_word_id; pid = p.tree_pos_id; rowbase = row; which = 0;
        out_f = p.tree_e;
    } else if (row < BB * TT + BB * LL) {
        wid = p.token_word_id; pid = p.token_pos_id; rowbase = row - BB * TT; which = 1;
        out_b = p.token_e;
    } else {
        wid = p.deque_word_id; pid = p.deque_pos_id; rowbase = row - BB * TT - BB * LL; which = 2;
        out_b = p.deque_e;
    }

    const int w  = wid[rowbase];
    const int pp = pid[rowbase];
    for (int e = u; e < WDIM + PDIM; e += 256) {
        s_e[e] = (e < WDIM) ? ld1<F32>(p.word_emb, (size_t)w * WDIM + e)
                            : ld1<F32>(p.pos_emb, (size_t)pp * PDIM + (e - WDIM));
    }
    __syncthreads();

    float acc = ld1<F32>(p.wd_b, u);
    for (int r = 0; r < WDIM + PDIM; ++r)
        acc = fmaf(s_e[r], ld1<F32>(p.wd_W, (size_t)r * UU + u), acc);
    acc = fmaxf(acc, 0.f);
    if (which == 0) out_f[(size_t)rowbase * UU + u] = acc;
    else            out_b[(size_t)rowbase * UU + u] = f2bf(acc);
}

__global__ __launch_bounds__(256) void embed_kernel(P p) {
    __shared__ __align__(16) float s_e[384];
    if (p.flag[0] == 1) embed_impl<true>(p, s_e);
    else                embed_impl<false>(p, s_e);
}

// ---------------------------------------------------------------------------
// One LSTM step over packed float4 weights. bz = {zi, zj, zf(+1 folded), zo} init.
// sched_barrier(0) keeps the 16 staged loads issued before the FMA block.
// ---------------------------------------------------------------------------
template<int R>
__device__ __forceinline__ float lstm_step_f4(const float4* __restrict__ Wp,
                                              const float4 bz,
                                              const float* __restrict__ s_xh,
                                              float& c) {
    float zi = bz.x, zj = bz.y, zf = bz.z, zo = bz.w;
    for (int r0 = 0; r0 < R; r0 += 16) {
        float4 w[16];
        #pragma unroll
        for (int k = 0; k < 16; ++k) w[k] = Wp[(size_t)(r0 + k) * 256];
        __builtin_amdgcn_sched_barrier(0);
        #pragma unroll
        for (int q = 0; q < 4; ++q) {
            const float4 x4 = *reinterpret_cast<const float4*>(s_xh + r0 + 4 * q);
            const float xv[4] = {x4.x, x4.y, x4.z, x4.w};
            #pragma unroll
            for (int j = 0; j < 4; ++j) {
                const float4 wv = w[4 * q + j];
                zi = fmaf(xv[j], wv.x, zi);
                zj = fmaf(xv[j], wv.y, zj);
                zf = fmaf(xv[j], wv.z, zf);
                zo = fmaf(xv[j], wv.w, zo);
            }
        }
    }
    const float nc = c * sigm(zf) + sigm(zi) * tanhf(zj);
    c = nc;
    return tanhf(nc) * sigm(zo);
}

template<bool F32>
__device__ __forceinline__ float4 load_bias4(const void* b, int u) {
    // gates i|j|f|o at cols u, 256+u, 512+u, 768+u; forget bias folded in.
    return make_float4(ld1<F32>(b, u), ld1<F32>(b, 256 + u),
                       ld1<F32>(b, 512 + u) + 1.0f, ld1<F32>(b, 768 + u));
}

__device__ __forceinline__ float4 zx_load(const uint2* __restrict__ zx, size_t n, int u) {
    const uint2 v = zx[n * 256 + u];
    const float2 ij = unp2h(v.x);
    const float2 fo = unp2h(v.y);
    return make_float4(ij.x, ij.y, fo.x, fo.y);
}

// ---------------------------------------------------------------------------
// Tree (shared by fallback and plan B — pkf rows [0,512), gates i|j|o|f)
// ---------------------------------------------------------------------------
template<bool F32>
__device__ void run_tree_f4(int b, const P& p, float* smem) {
    const int u = threadIdx.x;
    float* s_x  = smem;          // 256
    float* s_hj = smem + 256;    // 256
    float* s_hk = smem + 512;    // 1024
    float* H = p.H;
    float* C = p.C;
    H[(size_t)b * UU + u] = 0.f;
    C[(size_t)b * UU + u] = 0.f;

    const float4* __restrict__ Wt = p.pkf + u;                 // x rows [0,256)
    const float4* __restrict__ Wh = Wt + (size_t)256 * 256;    // h rows [256,512)
    const float bi = ld1<F32>(p.tree_b, u);
    const float bj = ld1<F32>(p.tree_b, 256 + u);
    const float bo = ld1<F32>(p.tree_b, 512 + u);
    const float bf = ld1<F32>(p.tree_b, 768 + u) + 1.0f;

    for (int i = 0; i < TT; ++i) {
        const int* co = p.children_order + ((size_t)b * TT + i) * KK;
        const int i0 = co[0], i1 = co[1], i2 = co[2], i3 = co[3];
        const float h0 = H[((size_t)i0 * BB + b) * UU + u];
        const float h1 = H[((size_t)i1 * BB + b) * UU + u];
        const float h2 = H[((size_t)i2 * BB + b) * UU + u];
        const float h3 = H[((size_t)i3 * BB + b) * UU + u];
        const float c0 = C[((size_t)i0 * BB + b) * UU + u];
        const float c1 = C[((size_t)i1 * BB + b) * UU + u];
        const float c2 = C[((size_t)i2 * BB + b) * UU + u];
        const float c3 = C[((size_t)i3 * BB + b) * UU + u];
        s_x[u]        = p.tree_e[((size_t)b * TT + i) * UU + u];
        s_hk[u]       = h0;
        s_hk[256 + u] = h1;
        s_hk[512 + u] = h2;
        s_hk[768 + u] = h3;
        s_hj[u]       = h0 + h1 + h2 + h3;
        __syncthreads();

        float zi = bi, zj = bj, zo = bo, fx = bf;
        for (int r0 = 0; r0 < 256; r0 += 16) {        // x rows
            float4 w[16];
            #pragma unroll
            for (int k = 0; k < 16; ++k) w[k] = Wt[(size_t)(r0 + k) * 256];
            __builtin_amdgcn_sched_barrier(0);
            #pragma unroll
            for (int q = 0; q < 4; ++q) {
                const float4 x4 = *reinterpret_cast<const float4*>(s_x + r0 + 4 * q);
                const float xv[4] = {x4.x, x4.y, x4.z, x4.w};
                #pragma unroll
                for (int j = 0; j < 4; ++j) {
                    const float4 wv = w[4 * q + j];
                    zi = fmaf(xv[j], wv.x, zi);
                    zj = fmaf(xv[j], wv.y, zj);
                    zo = fmaf(xv[j], wv.z, zo);
                    fx = fmaf(xv[j], wv.w, fx);
                }
            }
        }
        float f0 = 0.f, f1 = 0.f, f2 = 0.f, f3 = 0.f;
        for (int r0 = 0; r0 < 256; r0 += 16) {        // h rows
            float4 w[16];
            #pragma unroll
            for (int k = 0; k < 16; ++k) w[k] = Wh[(size_t)(r0 + k) * 256];
            __builtin_amdgcn_sched_barrier(0);
            #pragma unroll
            for (int q = 0; q < 4; ++q) {
                const int r = r0 + 4 * q;
                const float4 hj4 = *reinterpret_cast<const float4*>(s_hj + r);
                const float4 a0  = *reinterpret_cast<const float4*>(s_hk + r);
                const float4 a1  = *reinterpret_cast<const float4*>(s_hk + 256 + r);
                const float4 a2  = *reinterpret_cast<const float4*>(s_hk + 512 + r);
                const float4 a3  = *reinterpret_cast<const float4*>(s_hk + 768 + r);
                const float hjv[4] = {hj4.x, hj4.y, hj4.z, hj4.w};
                const float k0[4]  = {a0.x, a0.y, a0.z, a0.w};
                const float k1[4]  = {a1.x, a1.y, a1.z, a1.w};
                const float k2[4]  = {a2.x, a2.y, a2.z, a2.w};
                const float k3[4]  = {a3.x, a3.y, a3.z, a3.w};
                #pragma unroll
                for (int j = 0; j < 4; ++j) {
                    const float4 wv = w[4 * q + j];
                    zi = fmaf(hjv[j], wv.x, zi);
                    zj = fmaf(hjv[j], wv.y, zj);
                    zo = fmaf(hjv[j], wv.z, zo);
                    f0 = fmaf(k0[j], wv.w, f0);
                    f1 = fmaf(k1[j], wv.w, f1);
                    f2 = fmaf(k2[j], wv.w, f2);
                    f3 = fmaf(k3[j], wv.w, f3);
                }
            }
        }
        const float fsum = c0 * sigm(fx + f0) + c1 * sigm(fx + f1)
                         + c2 * sigm(fx + f2) + c3 * sigm(fx + f3);
        const float nc = fsum + sigm(zi) * tanhf(zj);
        const float nh = tanhf(nc) * sigm(zo);
        __syncthreads();
        H[((size_t)(i + 1) * BB + b) * UU + u] = nh;
        C[((size_t)(i + 1) * BB + b) * UU + u] = nc;
    }
}

// ===========================================================================
// FALLBACK (round-2) fused chains — used when workspace is too small
// ===========================================================================
template<bool F32>
__device__ void run_token_l0_f4(int b, const P& p, float* smem, bool is_bw) {
    const int u = threadIdx.x;
    float* s_xh = smem;
    const int len = p.token_length[b];
    const float4* __restrict__ Wp = p.pkf + (size_t)(is_bw ? OFF_BW0 : OFF_FW0) * 256 + u;
    const float4 bz = load_bias4<F32>(is_bw ? p.bw0_b : p.fw0_b, u);

    float c0 = 0.f;
    s_xh[256 + u] = 0.f;
    for (int t = 0; t < len; ++t) {
        const int row = is_bw ? (len - 1 - t) : t;
        s_xh[u] = bf2f(p.token_e[((size_t)b * LL + row) * UU + u]);
        __syncthreads();
        const float nh = lstm_step_f4<512>(Wp, bz, s_xh, c0);
        p.x1[((size_t)b * LL + row) * 512 + (is_bw ? 256 : 0) + u] = f2bf(nh);
        __syncthreads();
        s_xh[256 + u] = nh;
    }
}

template<bool F32>
__device__ void run_act_dq_f4(int b, const P& p, float* smem) {
    const int u = threadIdx.x;
    float* s_xh0 = smem;
    float* s_xh1 = smem + 512;

    {
        const int len = p.history_action_length[b];
        const float4* __restrict__ W0 = p.pkf + (size_t)OFF_ACT0 * 256 + u;
        const float4* __restrict__ W1 = p.pkf + (size_t)OFF_ACT1 * 256 + u;
        const float4 bz0 = load_bias4<F32>(p.act0_b, u);
        const float4 bz1 = load_bias4<F32>(p.act1_b, u);
        float ca0 = 0.f, ca1 = 0.f, h1last = 0.f;
        s_xh0[ADIM + u] = 0.f;
        s_xh1[256 + u]  = 0.f;
        for (int t = 0; t < len; ++t) {
            const int aid = p.history_action_id[b * AA + t];
            if (u < ADIM) s_xh0[u] = ld1<F32>(p.act_emb, (size_t)aid * ADIM + u);
            __syncthreads();
            const float nh0 = lstm_step_f4<320>(W0, bz0, s_xh0, ca0);
            __syncthreads();
            s_xh0[ADIM + u] = nh0;
            s_xh1[u]        = nh0;
            __syncthreads();
            const float nh1 = lstm_step_f4<512>(W1, bz1, s_xh1, ca1);
            __syncthreads();
            s_xh1[256 + u] = nh1;
            h1last = nh1;
        }
        p.act_h[b * UU + u] = h1last;
    }
    __syncthreads();
    {
        const int len = p.deque_length[b];
        const float4* __restrict__ W0 = p.pkf + (size_t)OFF_DQ0 * 256 + u;
        const float4* __restrict__ W1 = p.pkf + (size_t)OFF_DQ1 * 256 + u;
        const float4 bz0 = load_bias4<F32>(p.dq0_b, u);
        const float4 bz1 = load_bias4<F32>(p.dq1_b, u);
        float cd0 = 0.f, cd1 = 0.f, h1last = 0.f;
        s_xh0[256 + u] = 0.f;
        s_xh1[256 + u] = 0.f;
        for (int t = 0; t < len; ++t) {
            s_xh0[u] = bf2f(p.deque_e[((size_t)b * DQN + t) * UU + u]);
            __syncthreads();
            const float nh0 = lstm_step_f4<512>(W0, bz0, s_xh0, cd0);
            __syncthreads();
            s_xh0[256 + u] = nh0;
            s_xh1[u]       = nh0;
            __syncthreads();
            const float nh1 = lstm_step_f4<512>(W1, bz1, s_xh1, cd1);
            __syncthreads();
            s_xh1[256 + u] = nh1;
            h1last = nh1;
        }
        p.dq_h[b * UU + u] = h1last;
    }
}

__global__ __launch_bounds__(256) void phase1_fb_kernel(P p) {
    __shared__ __align__(16) float smem[1536];
    const bool f32 = (p.flag[0] == 1);
    const int chain = blockIdx.x & 3;
    const int b     = blockIdx.x >> 2;
    if (f32) {
        if (chain == 0)      run_tree_f4<true>(b, p, smem);
        else if (chain == 1) run_token_l0_f4<true>(b, p, smem, false);
        else if (chain == 2) run_token_l0_f4<true>(b, p, smem, true);
        else                 run_act_dq_f4<true>(b, p, smem);
    } else {
        if (chain == 0)      run_tree_f4<false>(b, p, smem);
        else if (chain == 1) run_token_l0_f4<false>(b, p, smem, false);
        else if (chain == 2) run_token_l0_f4<false>(b, p, smem, true);
        else                 run_act_dq_f4<false>(b, p, smem);
    }
}

template<bool F32>
__device__ void run_stack_f4(int b, const P& p, float* smem) {
    const int u = threadIdx.x;
    float* s_xh0 = smem;
    float* s_xh1 = smem + 512;
    const int len = p.stack_length[b];
    const float4* __restrict__ W0 = p.pkf + (size_t)OFF_S0 * 256 + u;
    const float4* __restrict__ W1 = p.pkf + (size_t)OFF_S1 * 256 + u;
    const float4 bz0 = load_bias4<F32>(p.stack0_b, u);
    const float4 bz1 = load_bias4<F32>(p.stack1_b, u);
    float cs0 = 0.f, cs1 = 0.f, h1last = 0.f;
    s_xh0[256 + u] = 0.f;
    s_xh1[256 + u] = 0.f;
    for (int t = 0; t < len; ++t) {
        const int so = p.stack_order[b * SS + t];
        s_xh0[u] = p.H[((size_t)so * BB + b) * UU + u];
        __syncthreads();
        const float nh0 = lstm_step_f4<512>(W0, bz0, s_xh0, cs0);
        __syncthreads();
        s_xh0[256 + u] = nh0;
        s_xh1[u]       = nh0;
        __syncthreads();
        const float nh1 = lstm_step_f4<512>(W1, bz1, s_xh1, cs1);
        __syncthreads();
        s_xh1[256 + u] = nh1;
        h1last = nh1;
    }
    p.stack_h[b * UU + u] = h1last;
}

template<bool F32>
__device__ void run_token_l1_f4(int b, const P& p, float* smem, bool is_bw) {
    const int u = threadIdx.x;
    float* s_xh = smem;
    const int len  = p.token_length[b];
    const int btop = p.buff_top_id[b];
    const float4* __restrict__ Wp = p.pkf + (size_t)(is_bw ? OFF_BW1 : OFF_FW1) * 256 + u;
    const float4 bz = load_bias4<F32>(is_bw ? p.bw1_b : p.fw1_b, u);

    float c1 = 0.f, hlast = 0.f;
    s_xh[512 + u] = 0.f;
    for (int t = 0; t < len; ++t) {
        const int row = is_bw ? (len - 1 - t) : t;
        const ushort_t* xr = p.x1 + ((size_t)b * LL + row) * 512;
        s_xh[u]       = bf2f(xr[u]);
        s_xh[256 + u] = bf2f(xr[256 + u]);
        __syncthreads();
        const float nh = lstm_step_f4<768>(Wp, bz, s_xh, c1);
        if (!is_bw) {
            if (t == btop) p.fw_top[b * UU + u] = nh;
        } else {
            if (t == 0)              p.bw_bottom[b * UU + u] = nh;
            if (t == len - 1 - btop) p.bw_top[b * UU + u]    = nh;
        }
        __syncthreads();
        s_xh[512 + u] = nh;
        hlast = nh;
    }
    if (!is_bw) p.fw1_h[b * UU + u] = hlast;
}

__global__ __launch_bounds__(256) void phase2_fb_kernel(P p) {
    __shared__ __align__(16) float smem[1024];
    const bool f32 = (p.flag[0] == 1);
    const int chain = blockIdx.x % 3;
    const int b     = blockIdx.x / 3;
    if (f32) {
        if (chain == 0)      run_stack_f4<true>(b, p, smem);
        else if (chain == 1) run_token_l1_f4<true>(b, p, smem, false);
        else                 run_token_l1_f4<true>(b, p, smem, true);
    } else {
        if (chain == 0)      run_stack_f4<false>(b, p, smem);
        else if (chain == 1) run_token_l1_f4<false>(b, p, smem, false);
        else                 run_token_l1_f4<false>(b, p, smem, true);
    }
}

// ===========================================================================
// PLAN B — x-part precompute (xpre, 32-row tiles / 32 KB LDS) + h-only recurrences
// ===========================================================================
template<bool F32, int R>
__device__ void xpre_compute(const void* __restrict__ W, const void* __restrict__ bias,
                             uint2* __restrict__ zx, int n0,
                             const float* __restrict__ s_xf, const ushort_t* __restrict__ s_xb) {
    const int u = threadIdx.x;
    const float4 bz = load_bias4<F32>(bias, u);
    for (int c = 0; c < 32; c += 8) {
        float4 acc[8];
        #pragma unroll
        for (int n = 0; n < 8; ++n) acc[n] = bz;
        for (int r0 = 0; r0 < R; r0 += 8) {
            float4 w[8];
            #pragma unroll
            for (int k = 0; k < 8; ++k) {
                const size_t ro = (size_t)(r0 + k) * 1024;
                w[k] = make_float4(ld1<F32>(W, ro + u),
                                   ld1<F32>(W, ro + 256 + u),
                                   ld1<F32>(W, ro + 512 + u),
                                   ld1<F32>(W, ro + 768 + u));
            }
            #pragma unroll
            for (int n = 0; n < 8; ++n) {
                float xv[8];
                #pragma unroll
                for (int k = 0; k < 8; ++k)
                    xv[k] = (R == 512) ? bf2f(s_xb[(size_t)(c + n) * 512 + r0 + k])
                                       : s_xf[(size_t)(c + n) * R + r0 + k];
                #pragma unroll
                for (int k = 0; k < 8; ++k) {
                    acc[n].x = fmaf(xv[k], w[k].x, acc[n].x);
                    acc[n].y = fmaf(xv[k], w[k].y, acc[n].y);
                    acc[n].z = fmaf(xv[k], w[k].z, acc[n].z);
                    acc[n].w = fmaf(xv[k], w[k].w, acc[n].w);
                }
            }
        }
        #pragma unroll
        for (int n = 0; n < 8; ++n) {
            uint2 v;
            v.x = pack2h(acc[n].x, acc[n].y);
            v.y = pack2h(acc[n].z, acc[n].w);
            zx[(size_t)(n0 + c + n) * 256 + u] = v;
        }
    }
}

template<bool F32, int STAGE>
__device__ void xpre_impl(const P& p, char* s_raw) {
    float*    s_xf = reinterpret_cast<float*>(s_raw);
    ushort_t* s_xb = reinterpret_cast<ushort_t*>(s_raw);
    const int blk = blockIdx.x;
    const int tid = threadIdx.x;

    const void* W; const void* bias; uint2* zx; int R; int kind; int n0;
    if (STAGE == 0) {
        if (blk < 256)      { W=p.fw0_W;  bias=p.fw0_b;  zx=p.zxA; R=256; kind=0; n0=blk*32; }
        else if (blk < 512) { W=p.bw0_W;  bias=p.bw0_b;  zx=p.zxB; R=256; kind=0; n0=(blk-256)*32; }
        else if (blk < 640) { W=p.act0_W; bias=p.act0_b; zx=p.zxC; R=64;  kind=3; n0=(blk-512)*32; }
        else                { W=p.dq0_W;  bias=p.dq0_b;  zx=p.zxD; R=256; kind=1; n0=(blk-640)*32; }
    } else if (STAGE == 1) {
        if (blk < 256)      { W=p.fw1_W;    bias=p.fw1_b;    zx=p.zxA; R=512; kind=2; n0=blk*32; }
        else if (blk < 512) { W=p.bw1_W;    bias=p.bw1_b;    zx=p.zxB; R=512; kind=2; n0=(blk-256)*32; }
        else if (blk < 640) { W=p.stack0_W; bias=p.stack0_b; zx=p.zxS; R=256; kind=4; n0=(blk-512)*32; }
        else if (blk < 768) { W=p.act1_W;   bias=p.act1_b;   zx=p.zxC; R=256; kind=5; n0=(blk-640)*32; }
        else                { W=p.dq1_W;    bias=p.dq1_b;    zx=p.zxD; R=256; kind=6; n0=(blk-768)*32; }
    } else {
        W=p.stack1_W; bias=p.stack1_b; zx=p.zxS; R=256; kind=7; n0=blk*32;
    }

    // stage the 32-row x tile into LDS (max 32 KB)
    if (kind == 0 || kind == 1) {                 // bf16 linear, R=256
        const ushort_t* src = (kind == 0 ? p.token_e : p.deque_e) + (size_t)n0 * 256;
        for (int i = tid; i < 32 * 256; i += 256) s_xf[i] = bf2f(src[i]);
    } else if (kind == 2) {                       // x1 bf16, R=512 (kept bf16 in LDS)
        const ushort_t* src = p.x1 + (size_t)n0 * 512;
        for (int i = tid; i < 32 * 512; i += 256) s_xb[i] = src[i];
    } else if (kind == 3) {                       // act_emb gather, R=64 (rows/batch = AA)
        const int b = n0 >> 6, t0 = n0 & 63;
        for (int i = tid; i < 32 * 64; i += 256) {
            const int t = t0 + (i >> 6), r = i & 63;
            int aid = p.history_action_id[b * AA + t];
            aid = aid < 0 ? 0 : (aid > NAOUT - 1 ? NAOUT - 1 : aid);   // clamp: abort-proof
            s_xf[i] = ld1<F32>(p.act_emb, (size_t)aid * ADIM + r);
        }
    } else if (kind == 4) {                       // H gather (stack0), R=256 (rows/batch = SS)
        const int b = n0 >> 6, t0 = n0 & 63;
        for (int i = tid; i < 32 * 256; i += 256) {
            const int t = t0 + (i >> 8), r = i & 255;
            int so = p.stack_order[b * SS + t];
            so = so < 0 ? 0 : (so > TT ? TT : so);                     // clamp: abort-proof
            s_xf[i] = p.H[((size_t)so * BB + b) * UU + r];
        }
    } else {                                      // f32 linear h0-seqs, R=256
        const float* src = (kind == 5 ? p.a0_seq : kind == 6 ? p.d0_seq : p.s0_seq)
                         + (size_t)n0 * 256;
        for (int i = tid; i < 32 * 256; i += 256) s_xf[i] = src[i];
    }
    __syncthreads();

    if (R == 512)      xpre_compute<F32, 512>(W, bias, zx, n0, s_xf, s_xb);
    else if (R == 256) xpre_compute<F32, 256>(W, bias, zx, n0, s_xf, s_xb);
    else               xpre_compute<F32, 64 >(W, bias, zx, n0, s_xf, s_xb);
}

__global__ __launch_bounds__(256) void xpre0_kernel(P p) {
    __shared__ __align__(16) char s_raw[32768];
    if (p.flag[0] == 1) xpre_impl<true, 0>(p, s_raw);
    else                xpre_impl<false, 0>(p, s_raw);
}
__global__ __launch_bounds__(256) void xpre1_kernel(P p) {
    __shared__ __align__(16) char s_raw[32768];
    if (p.flag[0] == 1) xpre_impl<true, 1>(p, s_raw);
    else                xpre_impl<false, 1>(p, s_raw);
}
__global__ __launch_bounds__(256) void xpre2_kernel(P p) {
    __shared__ __align__(16) char s_raw[32768];
    if (p.flag[0] == 1) xpre_impl<true, 2>(p, s_raw);
    else                xpre_impl<false, 2>(p, s_raw);
}

// ---------------------------------------------------------------------------
// Plan-B phase 1: {tree, fw0-h, bw0-h, act0-h, dq0-h}
// ---------------------------------------------------------------------------
template<bool F32>
__device__ void p1_impl(const P& p, float* smem) {
    const int chain = blockIdx.x >> 6;
    const int b     = blockIdx.x & 63;
    if (chain == 0) { run_tree_f4<F32>(b, p, smem); return; }

    const int u = threadIdx.x;
    float* s_h = smem;
    float c = 0.f;
    s_h[u] = 0.f;
    __syncthreads();

    if (chain == 1 || chain == 2) {               // token layer 0
        const bool bw = (chain == 2);
        const int len = p.token_length[b];
        const float4* __restrict__ Wh = p.pkf + (size_t)(bw ? PKH_BW0 : PKH_FW0) * 256 + u;
        const uint2* zx = bw ? p.zxB : p.zxA;
        for (int t = 0; t < len; ++t) {
            const int row = bw ? (len - 1 - t) : t;
            const float4 bz = zx_load(zx, (size_t)b * LL + row, u);
            const float nh = lstm_step_f4<256>(Wh, bz, s_h, c);
            p.x1[((size_t)b * LL + row) * 512 + (bw ? 256 : 0) + u] = f2bf(nh);
            __syncthreads();
            s_h[u] = nh;
            __syncthreads();
        }
    } else if (chain == 3) {                      // act layer 0
        const int len = p.history_action_length[b];
        const float4* __restrict__ Wh = p.pkf + (size_t)PKH_ACT0 * 256 + u;
        for (int t = 0; t < len; ++t) {
            const float4 bz = zx_load(p.zxC, (size_t)b * AA + t, u);
            const float nh = lstm_step_f4<256>(Wh, bz, s_h, c);
            p.a0_seq[((size_t)b * AA + t) * UU + u] = nh;
            __syncthreads();
            s_h[u] = nh;
            __syncthreads();
        }
    } else {                                      // deque layer 0
        const int len = p.deque_length[b];
        const float4* __restrict__ Wh = p.pkf + (size_t)PKH_DQ0 * 256 + u;
        for (int t = 0; t < len; ++t) {
            const float4 bz = zx_load(p.zxD, (size_t)b * DQN + t, u);
            const float nh = lstm_step_f4<256>(Wh, bz, s_h, c);
            p.d0_seq[((size_t)b * DQN + t) * UU + u] = nh;
            __syncthreads();
            s_h[u] = nh;
            __syncthreads();
        }
    }
}

__global__ __launch_bounds__(256) void p1_kernel(P p) {
    __shared__ __align__(16) float smem[1536];
    if (p.flag[0] == 1) p1_impl<true>(p, smem);
    else                p1_impl<false>(p, smem);
}

// ---------------------------------------------------------------------------
// Plan-B phase 2: {fw1-h, bw1-h, stack0-h, act1-h, dq1-h}
// ---------------------------------------------------------------------------
template<bool F32>
__device__ void p2_impl(const P& p, float* smem) {
    const int chain = blockIdx.x >> 6;
    const int b     = blockIdx.x & 63;
    const int u = threadIdx.x;
    float* s_h = smem;
    float c = 0.f;
    s_h[u] = 0.f;
    __syncthreads();

    if (chain == 0) {                             // fw1
        const int len  = p.token_length[b];
        const int btop = p.buff_top_id[b];
        const float4* __restrict__ Wh = p.pkf + (size_t)PKH_FW1 * 256 + u;
        float hlast = 0.f;
        for (int t = 0; t < len; ++t) {
            const float4 bz = zx_load(p.zxA, (size_t)b * LL + t, u);
            const float nh = lstm_step_f4<256>(Wh, bz, s_h, c);
            if (t == btop) p.fw_top[b * UU + u] = nh;
            __syncthreads();
            s_h[u] = nh;
            __syncthreads();
            hlast = nh;
        }
        p.fw1_h[b * UU + u] = hlast;
    } else if (chain == 1) {                      // bw1
        const int len  = p.token_length[b];
        const int btop = p.buff_top_id[b];
        const float4* __restrict__ Wh = p.pkf + (size_t)PKH_BW1 * 256 + u;
        for (int t = 0; t < len; ++t) {
            const int row = len - 1 - t;
            const float4 bz = zx_load(p.zxB, (size_t)b * LL + row, u);
            const float nh = lstm_step_f4<256>(Wh, bz, s_h, c);
            if (t == 0)              p.bw_bottom[b * UU + u] = nh;
            if (t == len - 1 - btop) p.bw_top[b * UU + u]    = nh;
            __syncthreads();
            s_h[u] = nh;
            __syncthreads();
        }
    } else if (chain == 2) {                      // stack layer 0
        const int len = p.stack_length[b];
        const float4* __restrict__ Wh = p.pkf + (size_t)PKH_S0 * 256 + u;
        for (int t = 0; t < len; ++t) {
            const float4 bz = zx_load(p.zxS, (size_t)b * SS + t, u);
            const float nh = lstm_step_f4<256>(Wh, bz, s_h, c);
            p.s0_seq[((size_t)b * SS + t) * UU + u] = nh;
            __syncthreads();
            s_h[u] = nh;
            __syncthreads();
        }
    } else if (chain == 3) {                      // act layer 1
        const int len = p.history_action_length[b];
        const float4* __restrict__ Wh = p.pkf + (size_t)PKH_ACT1 * 256 + u;
        float hlast = 0.f;
        for (int t = 0; t < len; ++t) {
            const float4 bz = zx_load(p.zxC, (size_t)b * AA + t, u);
            const float nh = lstm_step_f4<256>(Wh, bz, s_h, c);
            __syncthreads();
            s_h[u] = nh;
            __syncthreads();
            hlast = nh;
        }
        p.act_h[b * UU + u] = hlast;
    } else {                                      // deque layer 1
        const int len = p.deque_length[b];
        const float4* __restrict__ Wh = p.pkf + (size_t)PKH_DQ1 * 256 + u;
        float hlast = 0.f;
        for (int t = 0; t < len; ++t) {
            const float4 bz = zx_load(p.zxD, (size_t)b * DQN + t, u);
            const float nh = lstm_step_f4<256>(Wh, bz, s_h, c);
            __syncthreads();
            s_h[u] = nh;
            __syncthreads();
            hlast = nh;
        }
        p.dq_h[b * UU + u] = hlast;
    }
}

__global__ __launch_bounds__(256) void p2_kernel(P p) {
    __shared__ __align__(16) float smem[256];
    if (p.flag[0] == 1) p2_impl<true>(p, smem);
    else                p2_impl<false>(p, smem);
}

// ---------------------------------------------------------------------------
// Plan-B phase 3: stack layer 1
// ---------------------------------------------------------------------------
template<bool F32>
__device__ void p3_impl(const P& p, float* smem) {
    const int b = blockIdx.x;
    const int u = threadIdx.x;
    float* s_h = smem;
    float c = 0.f;
    s_h[u] = 0.f;
    __syncthreads();
    const int len = p.stack_length[b];
    const float4* __restrict__ Wh = p.pkf + (size_t)PKH_S1 * 256 + u;
    float hlast = 0.f;
    for (int t = 0; t < len; ++t) {
        const float4 bz = zx_load(p.zxS, (size_t)b * SS + t, u);
        const float nh = lstm_step_f4<256>(Wh, bz, s_h, c);
        __syncthreads();
        s_h[u] = nh;
        __syncthreads();
        hlast = nh;
    }
    p.stack_h[b * UU + u] = hlast;
}

__global__ __launch_bounds__(256) void p3_kernel(P p) {
    __shared__ __align__(16) float smem[256];
    if (p.flag[0] == 1) p3_impl<true>(p, smem);
    else                p3_impl<false>(p, smem);
}

// ---------------------------------------------------------------------------
// Final + pipeline tracers
// ---------------------------------------------------------------------------
template<bool F32>
__device__ __forceinline__ void st_out(void* out, int i, float v) {
    if constexpr (F32) reinterpret_cast<float*>(out)[i] = v;
    else               reinterpret_cast<__hip_bfloat16*>(out)[i] = __float2bfloat16(v);
}

template<bool F32>
__device__ void final_impl(const P& p, void* out, float* s_f) {
    const int b = blockIdx.x;
    const int u = threadIdx.x;
    s_f[u]        = p.stack_h[b * UU + u];
    s_f[256 + u]  = p.fw1_h[b * UU + u] - p.fw_top[b * UU + u];
    s_f[512 + u]  = p.bw_top[b * UU + u] - p.bw_bottom[b * UU + u];
    s_f[768 + u]  = p.act_h[b * UU + u];
    s_f[1024 + u] = p.dq_h[b * UU + u];
    __syncthreads();
    if (u < NAOUT) {
        float acc = ld1<F32>(p.fin_b, u);
        for (int r = 0; r < 1280; ++r)
            acc = fmaf(s_f[r], ld1<F32>(p.fin_W, (size_t)r * NAOUT + u), acc);
        acc = fmaxf(acc, 0.f);
        st_out<F32>(out, b * NAOUT + u, acc);
    }
    if (b == 0 && u == 0) {
        const uint_t POIS = 0xAAAAAAAAu;
        const uint_t* te = reinterpret_cast<const uint_t*>(p.tree_e);
        const uint_t* x1 = reinterpret_cast<const uint_t*>(p.x1);
        const uint_t* sh = reinterpret_cast<const uint_t*>(p.stack_h);
        bool te_p = true, x1_p = true;
        for (int i = 0; i < 8; ++i) { te_p &= (te[i] == POIS); x1_p &= (x1[i] == POIS); }
        bool sh_p = (sh[0] == POIS) && (sh[1] == POIS);
        float sent = 0.f;
        if (te_p)      sent = 3000.f;
        else if (x1_p) sent = 4000.f;
        else if (sh_p) sent = 5000.f;
        else if (*reinterpret_cast<const uint_t*>(p.flag) == POIS) sent = 6000.f;
        if (sent > 0.f) st_out<F32>(out, 0, sent);
    }
}

__global__ __launch_bounds__(256) void final_kernel(P p, void* out) {
    __shared__ __align__(16) float s_f[1280];
    if (p.flag[0] == 1) final_impl<true>(p, out, s_f);
    else                final_impl<false>(p, out, s_f);
}

// ---------------------------------------------------------------------------
extern "C" void kernel_launch(void* const* d_in, const int* in_sizes, int n_in,
                              void* d_out, int out_size, void* d_ws, size_t ws_size,
                              hipStream_t stream) {
    if (n_in != 43) {
        sentinel_kernel<<<1, 64, 0, stream>>>(d_out, 9000.f + (float)n_in);
        return;
    }
    if (out_size != NAOUT * BB) {
        sentinel_kernel<<<1, 64, 0, stream>>>(d_out, 8000.f);
        return;
    }

    P p;
    p.tree_word_id          = (const int*)d_in[0];
    p.tree_pos_id           = (const int*)d_in[1];
    p.token_word_id         = (const int*)d_in[2];
    p.token_pos_id          = (const int*)d_in[3];
    p.history_action_id     = (const int*)d_in[4];
    p.buff_top_id           = (const int*)d_in[5];
    p.deque_word_id         = (const int*)d_in[6];
    p.deque_pos_id          = (const int*)d_in[7];
    p.deque_length          = (const int*)d_in[8];
    p.children_order        = (const int*)d_in[9];
    p.stack_order           = (const int*)d_in[10];
    p.stack_length          = (const int*)d_in[11];
    p.token_length          = (const int*)d_in[12];
    p.history_action_length = (const int*)d_in[13];
    p.word_emb = d_in[14];
    p.pos_emb  = d_in[15];
    p.act_emb  = d_in[16];
    p.wd_W     = d_in[17];
    p.wd_b     = d_in[18];
    p.tree_W   = d_in[19];
    p.tree_b   = d_in[20];
    p.stack0_W = d_in[21];
    p.stack0_b = d_in[22];
    p.stack1_W = d_in[23];
    p.stack1_b = d_in[24];
    p.fw0_W    = d_in[25];
    p.fw0_b    = d_in[26];
    p.bw0_W    = d_in[27];
    p.bw0_b    = d_in[28];
    p.fw1_W    = d_in[29];
    p.fw1_b    = d_in[30];
    p.bw1_W    = d_in[31];
    p.bw1_b    = d_in[32];
    p.act0_W   = d_in[33];
    p.act0_b   = d_in[34];
    p.act1_W   = d_in[35];
    p.act1_b   = d_in[36];
    p.dq0_W    = d_in[37];
    p.dq0_b    = d_in[38];
    p.dq1_W    = d_in[39];
    p.dq1_b    = d_in[40];
    p.fin_W    = d_in[41];
    p.fin_b    = d_in[42];

    char* base = (char*)d_ws;

    // ---- Plan B layout (~112 MiB) ----
    size_t off = 0;
    p.flag = (int*)(base + off);           off += 256;
    p.stack_h   = (float*)(base + off);    off += (size_t)BB * UU * 4;
    p.fw1_h     = (float*)(base + off);    off += (size_t)BB * UU * 4;
    p.fw_top    = (float*)(base + off);    off += (size_t)BB * UU * 4;
    p.bw_top    = (float*)(base + off);    off += (size_t)BB * UU * 4;
    p.bw_bottom = (float*)(base + off);    off += (size_t)BB * UU * 4;
    p.act_h     = (float*)(base + off);    off += (size_t)BB * UU * 4;
    p.dq_h      = (float*)(base + off);    off += (size_t)BB * UU * 4;
    p.tree_e  = (float*)(base + off);      off += (size_t)BB * TT * UU * 4;
    p.token_e = (ushort_t*)(base + off);   off += (size_t)BB * LL * UU * 2;
    p.deque_e = (ushort_t*)(base + off);   off += (size_t)BB * DQN * UU * 2;
    p.x1      = (ushort_t*)(base + off);   off += (size_t)BB * LL * 512 * 2;
    p.a0_seq  = (float*)(base + off);      off += (size_t)BB * AA * UU * 4;
    p.d0_seq  = (float*)(base + off);      off += (size_t)BB * DQN * UU * 4;
    p.s0_seq  = (float*)(base + off);      off += (size_t)BB * SS * UU * 4;
    p.H       = (float*)(base + off);      off += (size_t)(TT + 1) * BB * UU * 4;
    p.C       = (float*)(base + off);      off += (size_t)(TT + 1) * BB * UU * 4;
    p.zxA     = (uint2*)(base + off);      off += (size_t)BB * LL * UU * 8;
    p.zxB     = (uint2*)(base + off);      off += (size_t)BB * LL * UU * 8;
    p.zxC     = (uint2*)(base + off);      off += (size_t)BB * AA * UU * 8;
    p.zxD     = (uint2*)(base + off);      off += (size_t)BB * DQN * UU * 8;
    p.zxS     = (uint2*)(base + off);      off += (size_t)BB * SS * UU * 8;
    p.pkf     = (float4*)(base + off);     off += (size_t)PK_ROWS_B * 256 * 16;
    const size_t planB_size = off;

    if (ws_size >= planB_size) {
        detect_kernel<<<1, 64, 0, stream>>>((const uint_t*)d_in[14], p.flag);
        pack_h_kernel<<<dim3(PK_ROWS_B), dim3(256), 0, stream>>>(p);
        embed_kernel<<<dim3(BB * TT + BB * LL + BB * DQN), dim3(256), 0, stream>>>(p);
        xpre0_kernel<<<dim3(704), dim3(256), 0, stream>>>(p);
        p1_kernel<<<dim3(5 * BB), dim3(256), 0, stream>>>(p);
        xpre1_kernel<<<dim3(832), dim3(256), 0, stream>>>(p);
        p2_kernel<<<dim3(5 * BB), dim3(256), 0, stream>>>(p);
        xpre2_kernel<<<dim3(128), dim3(256), 0, stream>>>(p);
        p3_kernel<<<dim3(BB), dim3(256), 0, stream>>>(p);
        final_kernel<<<dim3(BB), dim3(256), 0, stream>>>(p, d_out);
        return;
    }

    // ---- Fallback: round-2 layout (~62 MiB) ----
    off = 0;
    p.flag = (int*)(base + off);           off += 16;
    p.stack_h   = (float*)(base + off);    off += (size_t)BB * UU * 4;
    p.fw1_h     = (float*)(base + off);    off += (size_t)BB * UU * 4;
    p.fw_top    = (float*)(base + off);    off += (size_t)BB * UU * 4;
    p.bw_top    = (float*)(base + off);    off += (size_t)BB * UU * 4;
    p.bw_bottom = (float*)(base + off);    off += (size_t)BB * UU * 4;
    p.act_h     = (float*)(base + off);    off += (size_t)BB * UU * 4;
    p.dq_h      = (float*)(base + off);    off += (size_t)BB * UU * 4;
    p.tree_e  = (float*)(base + off);      off += (size_t)BB * TT * UU * 4;
    p.token_e = (ushort_t*)(base + off);   off += (size_t)BB * LL * UU * 2;
    p.deque_e = (ushort_t*)(base + off);   off += (size_t)BB * DQN * UU * 2;
    p.x1      = (ushort_t*)(base + off);   off += (size_t)BB * LL * 512 * 2;
    p.H       = (float*)(base + off);      off += (size_t)(TT + 1) * BB * UU * 4;
    p.C       = (float*)(base + off);      off += (size_t)(TT + 1) * BB * UU * 4;
    p.pkf     = (float4*)(base + off);     off += (size_t)PK_ROWS_FB * 256 * 16;
    // unused in fallback, but keep valid pointers
    p.a0_seq = p.d0_seq = p.s0_seq = (float*)base;
    p.zxA = p.zxB = p.zxC = p.zxD = p.zxS = (uint2*)base;

    if (ws_size < off) {
        sentinel_kernel<<<1, 64, 0, stream>>>(d_out, 7000.f + (float)(ws_size >> 20));
        return;
    }

    detect_kernel<<<1, 64, 0, stream>>>((const uint_t*)d_in[14], p.flag);
    pack_fb_kernel<<<dim3(PK_ROWS_FB), dim3(256), 0, stream>>>(p);
    embed_kernel<<<dim3(BB * TT + BB * LL + BB * DQN), dim3(256), 0, stream>>>(p);
    phase1_fb_kernel<<<dim3(4 * BB), dim3(256), 0, stream>>>(p);
    phase2_fb_kernel<<<dim3(3 * BB), dim3(256), 0, stream>>>(p);
    final_kernel<<<dim3(BB), dim3(256), 0, stream>>>(p, d_out);
}